// Round 1
// baseline (212.488 us; speedup 1.0000x reference)
//
#include <hip/hip_runtime.h>
#include <hip/hip_bf16.h>

typedef __attribute__((ext_vector_type(4))) float f32x4;
typedef __attribute__((ext_vector_type(2))) unsigned int u32x2;
typedef __attribute__((ext_vector_type(4))) unsigned int u32x4;
typedef __attribute__((ext_vector_type(8))) short bf16x8;

#define EPSF 1e-7f

// radial factor of logmap0(projx(expmap0(v*s, c), c), c)/s  applied to v, given sumsq(v)
__device__ __forceinline__ float radial_factor(float sumsq, float c, float s){
  float sc = sqrtf(c);
  float nv = sqrtf(sumsq);
  float nu = fmaxf(s*nv, EPSF);            // norm used in expmap0 (of v*s)
  float th = tanhf(sc*nu);
  float r1 = th/sc;                        // radius after expmap0
  float maxn = (1.0f - 1e-5f)/sc;
  float r2 = fminf(r1, maxn);              // radius after projx
  float n1 = fmaxf(r2, EPSF);              // norm recomputed in logmap0
  float a  = fminf(sc*n1, 1.0f - 1e-7f);
  float r3 = 0.5f*logf((1.0f + a)/(1.0f - a));   // artanh(a)
  return r3*r2/(sc*n1*nu);
}

__device__ __forceinline__ float gelu_f(float x){
  return 0.5f*x*(1.0f + erff(x*0.70710678118654752f));
}

__device__ __forceinline__ unsigned f2bf1(float f){   // RNE f32->bf16 (low 16 bits)
  unsigned u = __float_as_uint(f);
  return (u + 0x7FFFu + ((u>>16)&1u)) >> 16;
}
__device__ __forceinline__ unsigned f2bf_pk(float lo, float hi){
  unsigned ul = f2bf1(lo);
  unsigned uh = __float_as_uint(hi);
  uh = (uh + 0x7FFFu + ((uh>>16)&1u)) & 0xFFFF0000u;
  return ul | uh;
}

// ---------------- workspace layout (bytes) ----------------
// 0       Wc      bf16 [64][800]  (W_comb = W_tan@W_in, zero-padded K 784->800)
// 204800  bcomb   f32  [64]
// 205056  W0aE    f32  [32][64]   (W0a @ expm(S), row-major)
// 213248  brot0   f32  [5][64]    (b_own0 @ expm(-S))
// 214528  bown0   f32  [5][64]
// 215808  W0aT    f32  [64][32]   (W0aE transposed: [k][o])
// 224000  mb0     f32  [64]
// 224256  mb1     f32  [4]
// 224272  W1aE    f32  [16][4]    (W1a @ Mq)
#define WS_WC     0
#define WS_BCOMB  204800
#define WS_W0AE   205056
#define WS_BROT0  213248
#define WS_BOWN0  214528
#define WS_W0AT   215808
#define WS_MB0    224000
#define WS_MB1    224256
#define WS_W1AE   224272

// ============ prep A: W_comb (blocks 0..49) + exp row-actions (blocks 50..59) ============
__global__ __launch_bounds__(256) void prep_a(
    const float* __restrict__ W_in, const float* __restrict__ b_in,
    const float* __restrict__ W_tan, const float* __restrict__ b_tan,
    const float* __restrict__ A_rot, const float* __restrict__ W0a,
    const float* __restrict__ bp0,
    unsigned short* __restrict__ Wc, float* __restrict__ bcomb,
    float* __restrict__ W0aE, float* __restrict__ brot0, float* __restrict__ bown0)
{
  __shared__ __align__(16) float Al[64][68];
  __shared__ __align__(16) float ST[64][68];   // ST[j][m] = S[m][j], S = A - A^T
  const int bid = blockIdx.x, t = threadIdx.x;

  if (bid < 50){
    if (bid == 0 && t < 64){
      float s = b_tan[t];
      for (int j = 0; j < 128; ++j) s += b_in[j]*W_tan[t*128+j];
      bcomb[t] = s;
    }
    // W_comb: 64 rows x 200 groups of 4 k's
    const int g4 = bid*256 + t;              // 0..12799
    const int n = g4/200, k4 = (g4 - n*200)*4;
    f32x4 s = {0.f,0.f,0.f,0.f};
    if (k4 < 784){
      for (int j = 0; j < 128; ++j){
        float wt = W_tan[n*128+j];
        f32x4 wi = *(const f32x4*)(W_in + j*784 + k4);
        s += wt*wi;
      }
    }
    u32x2 st = { f2bf_pk(s[0], s[1]), f2bf_pk(s[2], s[3]) };
    *(u32x2*)(Wc + n*800 + k4) = st;
  } else {
    // exp(S) row actions
    for (int m = t; m < 4096; m += 256){
      int r = m >> 6, c = m & 63;
      Al[r][c] = A_rot[m];
    }
    __syncthreads();
    for (int m = t; m < 4096; m += 256){
      int r = m >> 6, c = m & 63;           // ST[r][c] = S[c][r] = A[c][r]-A[r][c]
      ST[r][c] = Al[c][r] - Al[r][c];
    }
    __syncthreads();
    const int wv = t >> 6, lane = t & 63;
    const int row = (bid - 50)*4 + wv;      // 0..39, active < 37
    if (row < 37){
      float v, sgn;
      if (row < 32){ v = W0a[row*64 + lane]; sgn = 1.f; }
      else {
        const int r = row - 32;
        float b = bp0[r*64 + lane];
        float ssq = b*b;
        #pragma unroll
        for (int d = 1; d < 64; d <<= 1) ssq += __shfl_xor(ssq, d);
        float fc = radial_factor(ssq, 1.0f, 1.0f);
        v = b*fc;
        bown0[r*64 + lane] = v;
        sgn = -1.f;
      }
      float acc = v;
      for (int k = 1; k <= 12; ++k){
        const float coef = sgn/(float)k;
        float nv = 0.f;
        #pragma unroll
        for (int m = 0; m < 64; m += 4){
          f32x4 s4 = *(const f32x4*)&ST[lane][m];
          nv += __int_as_float(__builtin_amdgcn_readlane(__float_as_int(v), m+0))*s4[0];
          nv += __int_as_float(__builtin_amdgcn_readlane(__float_as_int(v), m+1))*s4[1];
          nv += __int_as_float(__builtin_amdgcn_readlane(__float_as_int(v), m+2))*s4[2];
          nv += __int_as_float(__builtin_amdgcn_readlane(__float_as_int(v), m+3))*s4[3];
        }
        nv *= coef;
        v = nv; acc += nv;
      }
      if (row < 32) W0aE[row*64 + lane] = acc;
      else          brot0[(row-32)*64 + lane] = acc;
    }
  }
}

// ============ prep B: small folds (1 block x 256) ============
__global__ __launch_bounds__(256) void prep_small(
    const float* __restrict__ bp1,
    const float* __restrict__ p_quat, const float* __restrict__ q_quat,
    const float* __restrict__ b0a, const float* __restrict__ W0b, const float* __restrict__ b0b,
    const float* __restrict__ W1a,
    const float* __restrict__ W0aE, const float* __restrict__ brot0, const float* __restrict__ bown0,
    float* __restrict__ W0aT, float* __restrict__ mb0, float* __restrict__ mb1,
    float* __restrict__ W1aE)
{
  __shared__ float g[5][32];
  __shared__ float c1[5][4];
  __shared__ float fac1[3];
  __shared__ float Mq[4][4];
  const int t = threadIdx.x;

  for (int i = t; i < 2048; i += 256){
    int o = i >> 6, k = i & 63;
    W0aT[k*32 + o] = W0aE[i];
  }
  if (t < 64){
    float s = 0.f;
    for (int r = 0; r < 5; ++r) s += bown0[r*64 + t];
    mb0[t] = s * 0.2f;
  }
  if (t < 160){
    int r = t >> 5, o = t & 31;
    float s = b0a[o];
    for (int k = 0; k < 64; ++k) s += brot0[r*64+k]*W0aE[o*64+k];
    g[r][o] = gelu_f(s);
  }
  if (t >= 192 && t < 195){
    int r = t - 192;
    float ssq = 0.f;
    for (int j = 0; j < 4; ++j){ float b = bp1[r*4+j]; ssq += b*b; }
    fac1[r] = radial_factor(ssq, 0.8f, 1.0f);
  }
  if (t == 224){
    float pw=p_quat[0],px=p_quat[1],py=p_quat[2],pz=p_quat[3];
    float n1 = sqrtf(pw*pw+px*px+py*py+pz*pz) + EPSF;
    pw/=n1; px/=n1; py/=n1; pz/=n1;
    float qw=q_quat[0],qx=q_quat[1],qy=q_quat[2],qz=q_quat[3];
    float n2 = sqrtf(qw*qw+qx*qx+qy*qy+qz*qz) + EPSF;
    qw/=n2; qx/=n2; qy/=n2; qz/=n2;
    float Lp[4][4] = {{pw,-px,-py,-pz},{px,pw,-pz,py},{py,pz,pw,-px},{pz,-py,px,pw}};
    float Rq[4][4] = {{qw,-qx,-qy,-qz},{qx,qw,qz,-qy},{qy,-qz,qw,qx},{qz,qy,-qx,qw}};
    #pragma unroll
    for (int i = 0; i < 4; ++i)
      #pragma unroll
      for (int k = 0; k < 4; ++k){
        float s = 0.f;
        #pragma unroll
        for (int m = 0; m < 4; ++m) s += Rq[i][m]*Lp[m][k];
        Mq[i][k] = s;
      }
  }
  __syncthreads();
  if (t < 20){
    int r = t >> 2, o = t & 3;
    float s = b0b[o];
    for (int k = 0; k < 32; ++k) s += g[r][k]*W0b[o*32+k];
    c1[r][o] = s;
  }
  __syncthreads();
  if (t < 4){
    float s = 0.f;
    for (int r = 0; r < 3; ++r) s += bp1[r*4+t]*fac1[r];
    for (int r = 0; r < 5; ++r) s += c1[r][t];
    mb1[t] = s * 0.125f;
  }
  if (t >= 64 && t < 128){
    int i = t - 64, o = i >> 2, kq = i & 3;
    float s = 0.f;
    #pragma unroll
    for (int j = 0; j < 4; ++j) s += W1a[o*4+j]*Mq[j][kq];
    W1aE[o*4+kq] = s;
  }
}

// ============ main fused kernel: 64 rows per block ============
__global__ __launch_bounds__(256) void fused_main(
    const float* __restrict__ x,
    const unsigned short* __restrict__ Wc,
    const float* __restrict__ bcomb,
    const float* __restrict__ W0aT,
    const float* __restrict__ mb0g, const float* __restrict__ mb1g,
    const float* __restrict__ W1aEg,
    const float* __restrict__ b0a, const float* __restrict__ W0b, const float* __restrict__ b0b,
    const float* __restrict__ b1a, const float* __restrict__ W1b, const float* __restrict__ b1b,
    const float* __restrict__ Wout, const float* __restrict__ bout,
    float* __restrict__ out)
{
  __shared__ __align__(16) float vlds[64][72];   // v / v_tan0 [0..64), vt1 [64..68), vc1 [68..72)
  __shared__ __align__(16) float vt2[64][32];
  __shared__ __align__(16) float g0[64][32];
  __shared__ __align__(16) float g1[64][16];
  __shared__ __align__(16) float cmb0[64];
  __shared__ __align__(16) float cW0b[4][32];
  __shared__ __align__(16) float cW1b[32][16];
  __shared__ __align__(16) float cWout[10][100];
  __shared__ __align__(16) float cW1aE[16][4];
  __shared__ float cb0a[32], cb0b[4], cmb1[4], cb1a[16], cb1b[32], cbout[12];

  const int tid = threadIdx.x;

  // stage small constants into LDS (consumed only after later barriers)
  if (tid < 64)  cmb0[tid] = mb0g[tid];
  if (tid < 32)  cb0a[tid] = b0a[tid];
  if (tid < 128) ((float*)cW0b)[tid] = W0b[tid];
  if (tid < 4)   { cb0b[tid] = b0b[tid]; cmb1[tid] = mb1g[tid]; }
  if (tid < 64)  ((float*)cW1aE)[tid] = W1aEg[tid];
  if (tid < 16)  cb1a[tid] = b1a[tid];
  if (tid < 32)  cb1b[tid] = b1b[tid];
  if (tid < 10)  cbout[tid] = bout[tid];
  for (int i = tid; i < 512; i += 256)  ((float*)cW1b)[i] = W1b[i];
  for (int i = tid; i < 1000; i += 256) ((float*)cWout)[i] = Wout[i];

  // ---- GEMM: v[64][64] = x_tile @ W_comb^T + b_comb (bf16 MFMA 16x16x32) ----
  const int lane = tid & 63;
  const int w    = tid >> 6;
  const int wr   = w >> 1, wc = w & 1;
  const int lr   = lane & 15, lkg = lane >> 4;
  const size_t rowBase = (size_t)blockIdx.x * 64;
  const float* xp0 = x + (rowBase + (size_t)(wr*32 + lr)) * 784;
  const unsigned short* wb0 = Wc + (size_t)(wc*32 + lr) * 800;

  f32x4 acc[2][2] = {};
  for (int kk = 0; kk < 25; ++kk){
    const int k0 = kk*32 + lkg*8;
    bf16x8 afr[2];
    #pragma unroll
    for (int fi = 0; fi < 2; ++fi){
      f32x4 f0 = {0.f,0.f,0.f,0.f}, f1 = {0.f,0.f,0.f,0.f};
      if (k0 < 784){
        const f32x4* p = (const f32x4*)(xp0 + fi*(16*784) + k0);
        f0 = p[0]; f1 = p[1];
      }
      u32x4 pk = { f2bf_pk(f0[0], f0[1]), f2bf_pk(f0[2], f0[3]),
                   f2bf_pk(f1[0], f1[1]), f2bf_pk(f1[2], f1[3]) };
      afr[fi] = __builtin_bit_cast(bf16x8, pk);
    }
    bf16x8 bfr[2];
    #pragma unroll
    for (int fj = 0; fj < 2; ++fj)
      bfr[fj] = *(const bf16x8*)(wb0 + fj*(16*800) + k0);
    #pragma unroll
    for (int fi = 0; fi < 2; ++fi)
      #pragma unroll
      for (int fj = 0; fj < 2; ++fj)
        acc[fi][fj] = __builtin_amdgcn_mfma_f32_16x16x32_bf16(afr[fi], bfr[fj], acc[fi][fj], 0, 0, 0);
  }

  // epilogue: v -> LDS
  #pragma unroll
  for (int fi = 0; fi < 2; ++fi){
    #pragma unroll
    for (int fj = 0; fj < 2; ++fj){
      const int col = wc*32 + fj*16 + lr;
      const int r0  = wr*32 + fi*16 + lkg*4;
      const float bc = bcomb[col];
      #pragma unroll
      for (int j = 0; j < 4; ++j)
        vlds[r0 + j][col] = acc[fi][fj][j] + bc;
    }
  }
  __syncthreads();

  // ---- row phase: 4 threads per row ----
  const int row = tid >> 2, p4 = tid & 3;

  // R1: v_tan0 = radial(v)  (in place)
  {
    f32x4 rv[4];
    float* vptr = &vlds[row][p4*16];
    #pragma unroll
    for (int i = 0; i < 4; ++i) rv[i] = ((const f32x4*)vptr)[i];
    float ssq = 0.f;
    #pragma unroll
    for (int i = 0; i < 4; ++i)
      ssq += rv[i][0]*rv[i][0] + rv[i][1]*rv[i][1] + rv[i][2]*rv[i][2] + rv[i][3]*rv[i][3];
    ssq += __shfl_xor(ssq, 1); ssq += __shfl_xor(ssq, 2);
    const float fac = radial_factor(ssq, 1.0f, 1.0f);
    #pragma unroll
    for (int i = 0; i < 4; ++i){ rv[i] *= fac; ((f32x4*)vptr)[i] = rv[i]; }
  }
  __syncthreads();

  // R2: a0 = W0aE @ (2*vt0 - mb0) + b0a ; g0 = gelu(a0)   (8 outputs/thread)
  {
    const int og = p4;
    float a0o[8];
    #pragma unroll
    for (int j = 0; j < 8; ++j) a0o[j] = cb0a[og*8 + j];
    for (int k = 0; k < 64; k += 4){
      f32x4 vt = *(const f32x4*)&vlds[row][k];
      f32x4 mm = *(const f32x4*)&cmb0[k];
      #pragma unroll
      for (int u = 0; u < 4; ++u){
        const float vc = 2.f*vt[u] - mm[u];
        const f32x4* wp = (const f32x4*)(W0aT + (size_t)(k+u)*32 + og*8);
        f32x4 w0 = wp[0], w1 = wp[1];
        #pragma unroll
        for (int j = 0; j < 4; ++j){ a0o[j] += w0[j]*vc; a0o[4+j] += w1[j]*vc; }
      }
    }
    #pragma unroll
    for (int j = 0; j < 8; ++j) g0[row][og*8 + j] = gelu_f(a0o[j]);
  }
  __syncthreads();

  // R3: v1 = W0b@g0 + b0b (1 comp/thread); v_tan1, v_comb1
  {
    const int o1 = p4;
    float a1 = cb0b[o1];
    for (int k = 0; k < 32; k += 4){
      f32x4 gg = *(const f32x4*)&g0[row][k];
      f32x4 ww = *(const f32x4*)&cW0b[o1][k];
      a1 += gg[0]*ww[0] + gg[1]*ww[1] + gg[2]*ww[2] + gg[3]*ww[3];
    }
    float ss1 = a1*a1;
    ss1 += __shfl_xor(ss1, 1); ss1 += __shfl_xor(ss1, 2);
    const float f1v = radial_factor(ss1, 0.8f, 0.8f);
    const float vt1 = a1*f1v;
    vlds[row][64 + o1] = vt1;
    vlds[row][68 + o1] = 2.f*vt1 - cmb1[o1];
  }
  __syncthreads();

  // R4: a1 = W1aE @ vc1 + b1a ; g1 = gelu  (4 outputs/thread)
  {
    const f32x4 vc1 = *(const f32x4*)&vlds[row][68];
    #pragma unroll
    for (int j = 0; j < 4; ++j){
      const int o = p4*4 + j;
      float s1 = cb1a[o] + cW1aE[o][0]*vc1[0] + cW1aE[o][1]*vc1[1]
                         + cW1aE[o][2]*vc1[2] + cW1aE[o][3]*vc1[3];
      g1[row][o] = gelu_f(s1);
    }
  }
  __syncthreads();

  // R5: v2 = W1b@g1 + b1b (8/thread); v_tan2
  {
    float v2[8]; float ss2 = 0.f;
    #pragma unroll
    for (int j = 0; j < 8; ++j){
      const int o = p4*8 + j;
      float s = cb1b[o];
      for (int k = 0; k < 16; k += 4){
        f32x4 gg = *(const f32x4*)&g1[row][k];
        f32x4 ww = *(const f32x4*)&cW1b[o][k];
        s += gg[0]*ww[0] + gg[1]*ww[1] + gg[2]*ww[2] + gg[3]*ww[3];
      }
      v2[j] = s; ss2 += s*s;
    }
    ss2 += __shfl_xor(ss2, 1); ss2 += __shfl_xor(ss2, 2);
    const float f2v = radial_factor(ss2, 1.2f, 0.6f);
    #pragma unroll
    for (int j = 0; j < 8; ++j) vt2[row][p4*8 + j] = v2[j]*f2v;
  }
  __syncthreads();

  // R6: out = W_out @ concat(vt0, vt1, vt2) + b_out
  for (int idx = tid; idx < 640; idx += 256){
    const int r6 = idx/10, o = idx - r6*10;
    float s = cbout[o];
    const float* wrow = &cWout[o][0];
    const float* vrow = &vlds[r6][0];
    for (int k = 0; k < 68; k += 4){
      f32x4 a = *(const f32x4*)(vrow + k);
      f32x4 b = *(const f32x4*)(wrow + k);
      s += a[0]*b[0] + a[1]*b[1] + a[2]*b[2] + a[3]*b[3];
    }
    const float* v2row = &vt2[r6][0];
    for (int k = 0; k < 32; k += 4){
      f32x4 a = *(const f32x4*)(v2row + k);
      f32x4 b = *(const f32x4*)(wrow + 68 + k);
      s += a[0]*b[0] + a[1]*b[1] + a[2]*b[2] + a[3]*b[3];
    }
    out[(rowBase + (size_t)r6)*10 + o] = s;
  }
}

extern "C" void kernel_launch(void* const* d_in, const int* in_sizes, int n_in,
                              void* d_out, int out_size, void* d_ws, size_t ws_size,
                              hipStream_t stream)
{
  (void)n_in; (void)out_size; (void)ws_size;
  const float* x      = (const float*)d_in[0];
  const float* W_in   = (const float*)d_in[1];
  const float* b_in   = (const float*)d_in[2];
  const float* W_tan  = (const float*)d_in[3];
  const float* b_tan  = (const float*)d_in[4];
  const float* bp0    = (const float*)d_in[5];
  const float* bp1    = (const float*)d_in[6];
  /* bp2 = d_in[7] — dead in reference */
  const float* A_rot  = (const float*)d_in[8];
  const float* p_quat = (const float*)d_in[9];
  const float* q_quat = (const float*)d_in[10];
  const float* W0a    = (const float*)d_in[11];
  const float* b0a    = (const float*)d_in[12];
  const float* W0b    = (const float*)d_in[13];
  const float* b0b    = (const float*)d_in[14];
  const float* W1a    = (const float*)d_in[15];
  const float* b1a    = (const float*)d_in[16];
  const float* W1b    = (const float*)d_in[17];
  const float* b1b    = (const float*)d_in[18];
  const float* W_out  = (const float*)d_in[19];
  const float* b_out  = (const float*)d_in[20];

  char* ws = (char*)d_ws;
  unsigned short* Wc = (unsigned short*)(ws + WS_WC);
  float* bcomb = (float*)(ws + WS_BCOMB);
  float* W0aE  = (float*)(ws + WS_W0AE);
  float* brot0 = (float*)(ws + WS_BROT0);
  float* bown0 = (float*)(ws + WS_BOWN0);
  float* W0aT  = (float*)(ws + WS_W0AT);
  float* mb0   = (float*)(ws + WS_MB0);
  float* mb1   = (float*)(ws + WS_MB1);
  float* W1aE  = (float*)(ws + WS_W1AE);

  const int Brows = in_sizes[0] / 784;
  const int nblk  = Brows / 64;

  prep_a<<<60, 256, 0, stream>>>(W_in, b_in, W_tan, b_tan, A_rot, W0a, bp0,
                                 Wc, bcomb, W0aE, brot0, bown0);
  prep_small<<<1, 256, 0, stream>>>(bp1, p_quat, q_quat, b0a, W0b, b0b, W1a,
                                    W0aE, brot0, bown0, W0aT, mb0, mb1, W1aE);
  fused_main<<<nblk, 256, 0, stream>>>(x, Wc, bcomb, W0aT, mb0, mb1, W1aE,
                                       b0a, W0b, b0b, b1a, W1b, b1b,
                                       W_out, b_out, (float*)d_out);
}

// Round 2
// 194.755 us; speedup vs baseline: 1.0911x; 1.0911x over previous
//
#include <hip/hip_runtime.h>
#include <hip/hip_bf16.h>

typedef __attribute__((ext_vector_type(4))) float f32x4;
typedef __attribute__((ext_vector_type(2))) unsigned int u32x2;
typedef __attribute__((ext_vector_type(4))) unsigned int u32x4;
typedef __attribute__((ext_vector_type(8))) short bf16x8;

#define EPSF 1e-7f

// radial factor of logmap0(projx(expmap0(v*s, c), c), c)/s  applied to v, given sumsq(v)
__device__ __forceinline__ float radial_factor(float sumsq, float c, float s){
  float sc = sqrtf(c);
  float nv = sqrtf(sumsq);
  float nu = fmaxf(s*nv, EPSF);            // norm used in expmap0 (of v*s)
  float th = tanhf(sc*nu);
  float r1 = th/sc;                        // radius after expmap0
  float maxn = (1.0f - 1e-5f)/sc;
  float r2 = fminf(r1, maxn);              // radius after projx
  float n1 = fmaxf(r2, EPSF);              // norm recomputed in logmap0
  float a  = fminf(sc*n1, 1.0f - 1e-7f);
  float r3 = 0.5f*logf((1.0f + a)/(1.0f - a));   // artanh(a)
  return r3*r2/(sc*n1*nu);
}

__device__ __forceinline__ float gelu_f(float x){
  return 0.5f*x*(1.0f + erff(x*0.70710678118654752f));
}

__device__ __forceinline__ unsigned f2bf1(float f){   // RNE f32->bf16 (low 16 bits)
  unsigned u = __float_as_uint(f);
  return (u + 0x7FFFu + ((u>>16)&1u)) >> 16;
}
__device__ __forceinline__ unsigned f2bf_pk(float lo, float hi){
  unsigned ul = f2bf1(lo);
  unsigned uh = __float_as_uint(hi);
  uh = (uh + 0x7FFFu + ((uh>>16)&1u)) & 0xFFFF0000u;
  return ul | uh;
}

// ---------------- workspace layout (bytes) ----------------
#define WS_WC     0          // bf16 [64][800]
#define WS_BCOMB  204800     // f32 [64]
#define WS_W0AE   205056     // f32 [32][64]
#define WS_BROT0  213248     // f32 [5][64]
#define WS_BOWN0  214528     // f32 [5][64]
#define WS_W0AT   215808     // f32 [64][32]
#define WS_MB0    224000     // f32 [64]
#define WS_MB1    224256     // f32 [4]
#define WS_W1AE   224272     // f32 [16][4]
#define WS_V      225280     // f32 [B][64]

// ============ prep A: W_comb (blocks 0..49) + exp row-actions (blocks 50..59) ============
__global__ __launch_bounds__(256) void prep_a(
    const float* __restrict__ W_in, const float* __restrict__ b_in,
    const float* __restrict__ W_tan, const float* __restrict__ b_tan,
    const float* __restrict__ A_rot, const float* __restrict__ W0a,
    const float* __restrict__ bp0,
    unsigned short* __restrict__ Wc, float* __restrict__ bcomb,
    float* __restrict__ W0aE, float* __restrict__ brot0, float* __restrict__ bown0)
{
  __shared__ __align__(16) float Al[64][68];
  __shared__ __align__(16) float ST[64][68];   // ST[j][m] = S[m][j], S = A - A^T
  const int bid = blockIdx.x, t = threadIdx.x;

  if (bid < 50){
    if (bid == 0 && t < 64){
      float s = b_tan[t];
      for (int j = 0; j < 128; ++j) s += b_in[j]*W_tan[t*128+j];
      bcomb[t] = s;
    }
    const int g4 = bid*256 + t;              // 0..12799
    const int n = g4/200, k4 = (g4 - n*200)*4;
    f32x4 s = {0.f,0.f,0.f,0.f};
    if (k4 < 784){
      for (int j = 0; j < 128; ++j){
        float wt = W_tan[n*128+j];
        f32x4 wi = *(const f32x4*)(W_in + j*784 + k4);
        s += wt*wi;
      }
    }
    u32x2 st = { f2bf_pk(s[0], s[1]), f2bf_pk(s[2], s[3]) };
    *(u32x2*)(Wc + n*800 + k4) = st;
  } else {
    for (int m = t; m < 4096; m += 256){
      int r = m >> 6, c = m & 63;
      Al[r][c] = A_rot[m];
    }
    __syncthreads();
    for (int m = t; m < 4096; m += 256){
      int r = m >> 6, c = m & 63;
      ST[r][c] = Al[c][r] - Al[r][c];
    }
    __syncthreads();
    const int wv = t >> 6, lane = t & 63;
    const int row = (bid - 50)*4 + wv;      // 0..39, active < 37
    if (row < 37){
      float v, sgn;
      if (row < 32){ v = W0a[row*64 + lane]; sgn = 1.f; }
      else {
        const int r = row - 32;
        float b = bp0[r*64 + lane];
        float ssq = b*b;
        #pragma unroll
        for (int d = 1; d < 64; d <<= 1) ssq += __shfl_xor(ssq, d);
        float fc = radial_factor(ssq, 1.0f, 1.0f);
        v = b*fc;
        bown0[r*64 + lane] = v;
        sgn = -1.f;
      }
      float acc = v;
      for (int k = 1; k <= 12; ++k){
        const float coef = sgn/(float)k;
        float nv = 0.f;
        #pragma unroll
        for (int m = 0; m < 64; m += 4){
          f32x4 s4 = *(const f32x4*)&ST[lane][m];
          nv += __int_as_float(__builtin_amdgcn_readlane(__float_as_int(v), m+0))*s4[0];
          nv += __int_as_float(__builtin_amdgcn_readlane(__float_as_int(v), m+1))*s4[1];
          nv += __int_as_float(__builtin_amdgcn_readlane(__float_as_int(v), m+2))*s4[2];
          nv += __int_as_float(__builtin_amdgcn_readlane(__float_as_int(v), m+3))*s4[3];
        }
        nv *= coef;
        v = nv; acc += nv;
      }
      if (row < 32) W0aE[row*64 + lane] = acc;
      else          brot0[(row-32)*64 + lane] = acc;
    }
  }
}

// ============ prep B: small folds (1 block x 256) ============
__global__ __launch_bounds__(256) void prep_small(
    const float* __restrict__ bp1,
    const float* __restrict__ p_quat, const float* __restrict__ q_quat,
    const float* __restrict__ b0a, const float* __restrict__ W0b, const float* __restrict__ b0b,
    const float* __restrict__ W1a,
    const float* __restrict__ W0aE, const float* __restrict__ brot0, const float* __restrict__ bown0,
    float* __restrict__ W0aT, float* __restrict__ mb0, float* __restrict__ mb1,
    float* __restrict__ W1aE)
{
  __shared__ float g[5][32];
  __shared__ float c1[5][4];
  __shared__ float fac1[3];
  __shared__ float Mq[4][4];
  const int t = threadIdx.x;

  for (int i = t; i < 2048; i += 256){
    int o = i >> 6, k = i & 63;
    W0aT[k*32 + o] = W0aE[i];
  }
  if (t < 64){
    float s = 0.f;
    for (int r = 0; r < 5; ++r) s += bown0[r*64 + t];
    mb0[t] = s * 0.2f;
  }
  if (t < 160){
    int r = t >> 5, o = t & 31;
    float s = b0a[o];
    for (int k = 0; k < 64; ++k) s += brot0[r*64+k]*W0aE[o*64+k];
    g[r][o] = gelu_f(s);
  }
  if (t >= 192 && t < 195){
    int r = t - 192;
    float ssq = 0.f;
    for (int j = 0; j < 4; ++j){ float b = bp1[r*4+j]; ssq += b*b; }
    fac1[r] = radial_factor(ssq, 0.8f, 1.0f);
  }
  if (t == 224){
    float pw=p_quat[0],px=p_quat[1],py=p_quat[2],pz=p_quat[3];
    float n1 = sqrtf(pw*pw+px*px+py*py+pz*pz) + EPSF;
    pw/=n1; px/=n1; py/=n1; pz/=n1;
    float qw=q_quat[0],qx=q_quat[1],qy=q_quat[2],qz=q_quat[3];
    float n2 = sqrtf(qw*qw+qx*qx+qy*qy+qz*qz) + EPSF;
    qw/=n2; qx/=n2; qy/=n2; qz/=n2;
    float Lp[4][4] = {{pw,-px,-py,-pz},{px,pw,-pz,py},{py,pz,pw,-px},{pz,-py,px,pw}};
    float Rq[4][4] = {{qw,-qx,-qy,-qz},{qx,qw,qz,-qy},{qy,-qz,qw,qx},{qz,qy,-qx,qw}};
    #pragma unroll
    for (int i = 0; i < 4; ++i)
      #pragma unroll
      for (int k = 0; k < 4; ++k){
        float s = 0.f;
        #pragma unroll
        for (int m = 0; m < 4; ++m) s += Rq[i][m]*Lp[m][k];
        Mq[i][k] = s;
      }
  }
  __syncthreads();
  if (t < 20){
    int r = t >> 2, o = t & 3;
    float s = b0b[o];
    for (int k = 0; k < 32; ++k) s += g[r][k]*W0b[o*32+k];
    c1[r][o] = s;
  }
  __syncthreads();
  if (t < 4){
    float s = 0.f;
    for (int r = 0; r < 3; ++r) s += bp1[r*4+t]*fac1[r];
    for (int r = 0; r < 5; ++r) s += c1[r][t];
    mb1[t] = s * 0.125f;
  }
  if (t >= 64 && t < 128){
    int i = t - 64, o = i >> 2, kq = i & 3;
    float s = 0.f;
    #pragma unroll
    for (int j = 0; j < 4; ++j) s += W1a[o*4+j]*Mq[j][kq];
    W1aE[o*4+kq] = s;
  }
}

// ============ kernel 1: v = x @ Wc^T + bcomb (lean, high-occupancy) ============
__global__ __launch_bounds__(256, 4) void gemm_v(
    const float* __restrict__ x,
    const unsigned short* __restrict__ Wc,
    const float* __restrict__ bcomb,
    float* __restrict__ v)
{
  __shared__ __align__(16) float vt[64][68];
  const int tid  = threadIdx.x;
  const int lane = tid & 63;
  const int w    = tid >> 6;
  const int wr   = w >> 1, wc = w & 1;
  const int lr   = lane & 15, lkg = lane >> 4;
  const size_t rowBase = (size_t)blockIdx.x * 64;
  const float* xp0 = x + (rowBase + (size_t)(wr*32 + lr)) * 784;
  const unsigned short* wb0 = Wc + (size_t)(wc*32 + lr) * 800;

  f32x4 acc[2][2] = {};
  f32x4 f[4];
  {
    const int k0 = lkg*8;
    const f32x4* p0 = (const f32x4*)(xp0 + k0);
    const f32x4* p1 = (const f32x4*)(xp0 + 16*784 + k0);
    f[0] = p0[0]; f[1] = p0[1]; f[2] = p1[0]; f[3] = p1[1];
  }
  for (int kk = 0; kk < 25; ++kk){
    const int k0 = kk*32 + lkg*8;
    f32x4 fn[4] = {{0.f,0.f,0.f,0.f},{0.f,0.f,0.f,0.f},{0.f,0.f,0.f,0.f},{0.f,0.f,0.f,0.f}};
    const int k1 = k0 + 32;
    if (kk < 24 && k1 < 784){
      const f32x4* p0 = (const f32x4*)(xp0 + k1);
      const f32x4* p1 = (const f32x4*)(xp0 + 16*784 + k1);
      fn[0] = p0[0]; fn[1] = p0[1]; fn[2] = p1[0]; fn[3] = p1[1];
    }
    u32x4 pk0 = { f2bf_pk(f[0][0], f[0][1]), f2bf_pk(f[0][2], f[0][3]),
                  f2bf_pk(f[1][0], f[1][1]), f2bf_pk(f[1][2], f[1][3]) };
    u32x4 pk1 = { f2bf_pk(f[2][0], f[2][1]), f2bf_pk(f[2][2], f[2][3]),
                  f2bf_pk(f[3][0], f[3][1]), f2bf_pk(f[3][2], f[3][3]) };
    bf16x8 afr0 = __builtin_bit_cast(bf16x8, pk0);
    bf16x8 afr1 = __builtin_bit_cast(bf16x8, pk1);
    bf16x8 bfr0 = *(const bf16x8*)(wb0 + k0);
    bf16x8 bfr1 = *(const bf16x8*)(wb0 + 16*800 + k0);
    acc[0][0] = __builtin_amdgcn_mfma_f32_16x16x32_bf16(afr0, bfr0, acc[0][0], 0, 0, 0);
    acc[0][1] = __builtin_amdgcn_mfma_f32_16x16x32_bf16(afr0, bfr1, acc[0][1], 0, 0, 0);
    acc[1][0] = __builtin_amdgcn_mfma_f32_16x16x32_bf16(afr1, bfr0, acc[1][0], 0, 0, 0);
    acc[1][1] = __builtin_amdgcn_mfma_f32_16x16x32_bf16(afr1, bfr1, acc[1][1], 0, 0, 0);
    f[0] = fn[0]; f[1] = fn[1]; f[2] = fn[2]; f[3] = fn[3];
  }

  // LDS transpose for coalesced v stores
  #pragma unroll
  for (int fi = 0; fi < 2; ++fi){
    #pragma unroll
    for (int fj = 0; fj < 2; ++fj){
      const int col = wc*32 + fj*16 + lr;
      const int r0  = wr*32 + fi*16 + lkg*4;
      const float bc = bcomb[col];
      #pragma unroll
      for (int j = 0; j < 4; ++j)
        vt[r0 + j][col] = acc[fi][fj][j] + bc;
    }
  }
  __syncthreads();
  const int row = tid >> 2, seg = tid & 3;
  float* dst = v + (rowBase + (size_t)row)*64 + seg*16;
  const float* src = &vt[row][seg*16];
  #pragma unroll
  for (int i = 0; i < 4; ++i)
    ((f32x4*)dst)[i] = ((const f32x4*)src)[i];
}

// ============ kernel 2: row phase (radial + MLP chain + head) ============
__global__ __launch_bounds__(256, 4) void row_phase(
    const float* __restrict__ v,
    const float* __restrict__ W0aT,
    const float* __restrict__ mb0g, const float* __restrict__ mb1g,
    const float* __restrict__ W1aEg,
    const float* __restrict__ b0a, const float* __restrict__ W0b, const float* __restrict__ b0b,
    const float* __restrict__ b1a, const float* __restrict__ W1b, const float* __restrict__ b1b,
    const float* __restrict__ Wout, const float* __restrict__ bout,
    float* __restrict__ out)
{
  __shared__ __align__(16) float vlds[64][72];   // vt0 [0..64), vt1 [64..68), vc1 [68..72)
  __shared__ __align__(16) float vt2[64][32];
  __shared__ __align__(16) float g0[64][32];
  __shared__ __align__(16) float g1[64][16];
  __shared__ __align__(16) float cmb0[64];
  __shared__ __align__(16) float cW0b[4][32];
  __shared__ __align__(16) float cW1b[32][16];
  __shared__ __align__(16) float cWout[10][100];
  __shared__ __align__(16) float cW1aE[16][4];
  __shared__ float cb0a[32], cb0b[4], cmb1[4], cb1a[16], cb1b[32], cbout[12];

  const int tid = threadIdx.x;
  const size_t rowBase = (size_t)blockIdx.x * 64;

  // load v tile (coalesced)
  for (int i = tid; i < 1024; i += 256){
    const int r = i >> 4, seg = i & 15;
    *(f32x4*)&vlds[r][seg*4] = *(const f32x4*)(v + (rowBase + (size_t)r)*64 + seg*4);
  }
  // stage small constants
  if (tid < 64)  cmb0[tid] = mb0g[tid];
  if (tid < 32)  cb0a[tid] = b0a[tid];
  if (tid < 128) ((float*)cW0b)[tid] = W0b[tid];
  if (tid < 4)   { cb0b[tid] = b0b[tid]; cmb1[tid] = mb1g[tid]; }
  if (tid < 64)  ((float*)cW1aE)[tid] = W1aEg[tid];
  if (tid < 16)  cb1a[tid] = b1a[tid];
  if (tid < 32)  cb1b[tid] = b1b[tid];
  if (tid < 10)  cbout[tid] = bout[tid];
  for (int i = tid; i < 512; i += 256)  ((float*)cW1b)[i] = W1b[i];
  for (int i = tid; i < 1000; i += 256) ((float*)cWout)[i] = Wout[i];
  __syncthreads();

  const int row = tid >> 2, p4 = tid & 3;

  // R1: v_tan0 = radial(v)  (in place)
  {
    f32x4 rv[4];
    float* vptr = &vlds[row][p4*16];
    #pragma unroll
    for (int i = 0; i < 4; ++i) rv[i] = ((const f32x4*)vptr)[i];
    float ssq = 0.f;
    #pragma unroll
    for (int i = 0; i < 4; ++i)
      ssq += rv[i][0]*rv[i][0] + rv[i][1]*rv[i][1] + rv[i][2]*rv[i][2] + rv[i][3]*rv[i][3];
    ssq += __shfl_xor(ssq, 1); ssq += __shfl_xor(ssq, 2);
    const float fac = radial_factor(ssq, 1.0f, 1.0f);
    #pragma unroll
    for (int i = 0; i < 4; ++i){ rv[i] *= fac; ((f32x4*)vptr)[i] = rv[i]; }
  }
  __syncthreads();

  // R2: a0 = W0aE @ (2*vt0 - mb0) + b0a ; g0 = gelu(a0)   (8 outputs/thread)
  {
    const int og = p4;
    float a0o[8];
    #pragma unroll
    for (int j = 0; j < 8; ++j) a0o[j] = cb0a[og*8 + j];
    for (int k = 0; k < 64; k += 4){
      f32x4 vtv = *(const f32x4*)&vlds[row][k];
      f32x4 mm = *(const f32x4*)&cmb0[k];
      #pragma unroll
      for (int u = 0; u < 4; ++u){
        const float vc = 2.f*vtv[u] - mm[u];
        const f32x4* wp = (const f32x4*)(W0aT + (size_t)(k+u)*32 + og*8);
        f32x4 w0 = wp[0], w1 = wp[1];
        #pragma unroll
        for (int j = 0; j < 4; ++j){ a0o[j] += w0[j]*vc; a0o[4+j] += w1[j]*vc; }
      }
    }
    #pragma unroll
    for (int j = 0; j < 8; ++j) g0[row][og*8 + j] = gelu_f(a0o[j]);
  }
  __syncthreads();

  // R3: v1 = W0b@g0 + b0b (1 comp/thread); v_tan1, v_comb1
  {
    const int o1 = p4;
    float a1 = cb0b[o1];
    for (int k = 0; k < 32; k += 4){
      f32x4 gg = *(const f32x4*)&g0[row][k];
      f32x4 ww = *(const f32x4*)&cW0b[o1][k];
      a1 += gg[0]*ww[0] + gg[1]*ww[1] + gg[2]*ww[2] + gg[3]*ww[3];
    }
    float ss1 = a1*a1;
    ss1 += __shfl_xor(ss1, 1); ss1 += __shfl_xor(ss1, 2);
    const float f1v = radial_factor(ss1, 0.8f, 0.8f);
    const float vt1 = a1*f1v;
    vlds[row][64 + o1] = vt1;
    vlds[row][68 + o1] = 2.f*vt1 - cmb1[o1];
  }
  __syncthreads();

  // R4: a1 = W1aE @ vc1 + b1a ; g1 = gelu  (4 outputs/thread)
  {
    const f32x4 vc1 = *(const f32x4*)&vlds[row][68];
    #pragma unroll
    for (int j = 0; j < 4; ++j){
      const int o = p4*4 + j;
      float s1 = cb1a[o] + cW1aE[o][0]*vc1[0] + cW1aE[o][1]*vc1[1]
                         + cW1aE[o][2]*vc1[2] + cW1aE[o][3]*vc1[3];
      g1[row][o] = gelu_f(s1);
    }
  }
  __syncthreads();

  // R5: v2 = W1b@g1 + b1b (8/thread); v_tan2
  {
    float v2[8]; float ss2 = 0.f;
    #pragma unroll
    for (int j = 0; j < 8; ++j){
      const int o = p4*8 + j;
      float s = cb1b[o];
      for (int k = 0; k < 16; k += 4){
        f32x4 gg = *(const f32x4*)&g1[row][k];
        f32x4 ww = *(const f32x4*)&cW1b[o][k];
        s += gg[0]*ww[0] + gg[1]*ww[1] + gg[2]*ww[2] + gg[3]*ww[3];
      }
      v2[j] = s; ss2 += s*s;
    }
    ss2 += __shfl_xor(ss2, 1); ss2 += __shfl_xor(ss2, 2);
    const float f2v = radial_factor(ss2, 1.2f, 0.6f);
    #pragma unroll
    for (int j = 0; j < 8; ++j) vt2[row][p4*8 + j] = v2[j]*f2v;
  }
  __syncthreads();

  // R6: out = W_out @ concat(vt0, vt1, vt2) + b_out
  for (int idx = tid; idx < 640; idx += 256){
    const int r6 = idx/10, o = idx - r6*10;
    float s = cbout[o];
    const float* wrow = &cWout[o][0];
    const float* vrow = &vlds[r6][0];
    for (int k = 0; k < 68; k += 4){
      f32x4 a = *(const f32x4*)(vrow + k);
      f32x4 b = *(const f32x4*)(wrow + k);
      s += a[0]*b[0] + a[1]*b[1] + a[2]*b[2] + a[3]*b[3];
    }
    const float* v2row = &vt2[r6][0];
    for (int k = 0; k < 32; k += 4){
      f32x4 a = *(const f32x4*)(v2row + k);
      f32x4 b = *(const f32x4*)(wrow + 68 + k);
      s += a[0]*b[0] + a[1]*b[1] + a[2]*b[2] + a[3]*b[3];
    }
    out[(rowBase + (size_t)r6)*10 + o] = s;
  }
}

// ============ fallback: original fused kernel (used only if ws too small) ============
__global__ __launch_bounds__(256) void fused_main(
    const float* __restrict__ x,
    const unsigned short* __restrict__ Wc,
    const float* __restrict__ bcomb,
    const float* __restrict__ W0aT,
    const float* __restrict__ mb0g, const float* __restrict__ mb1g,
    const float* __restrict__ W1aEg,
    const float* __restrict__ b0a, const float* __restrict__ W0b, const float* __restrict__ b0b,
    const float* __restrict__ b1a, const float* __restrict__ W1b, const float* __restrict__ b1b,
    const float* __restrict__ Wout, const float* __restrict__ bout,
    float* __restrict__ out)
{
  __shared__ __align__(16) float vlds[64][72];
  __shared__ __align__(16) float vt2[64][32];
  __shared__ __align__(16) float g0[64][32];
  __shared__ __align__(16) float g1[64][16];
  __shared__ __align__(16) float cmb0[64];
  __shared__ __align__(16) float cW0b[4][32];
  __shared__ __align__(16) float cW1b[32][16];
  __shared__ __align__(16) float cWout[10][100];
  __shared__ __align__(16) float cW1aE[16][4];
  __shared__ float cb0a[32], cb0b[4], cmb1[4], cb1a[16], cb1b[32], cbout[12];

  const int tid = threadIdx.x;

  if (tid < 64)  cmb0[tid] = mb0g[tid];
  if (tid < 32)  cb0a[tid] = b0a[tid];
  if (tid < 128) ((float*)cW0b)[tid] = W0b[tid];
  if (tid < 4)   { cb0b[tid] = b0b[tid]; cmb1[tid] = mb1g[tid]; }
  if (tid < 64)  ((float*)cW1aE)[tid] = W1aEg[tid];
  if (tid < 16)  cb1a[tid] = b1a[tid];
  if (tid < 32)  cb1b[tid] = b1b[tid];
  if (tid < 10)  cbout[tid] = bout[tid];
  for (int i = tid; i < 512; i += 256)  ((float*)cW1b)[i] = W1b[i];
  for (int i = tid; i < 1000; i += 256) ((float*)cWout)[i] = Wout[i];

  const int lane = tid & 63;
  const int w    = tid >> 6;
  const int wr   = w >> 1, wc = w & 1;
  const int lr   = lane & 15, lkg = lane >> 4;
  const size_t rowBase = (size_t)blockIdx.x * 64;
  const float* xp0 = x + (rowBase + (size_t)(wr*32 + lr)) * 784;
  const unsigned short* wb0 = Wc + (size_t)(wc*32 + lr) * 800;

  f32x4 acc[2][2] = {};
  for (int kk = 0; kk < 25; ++kk){
    const int k0 = kk*32 + lkg*8;
    bf16x8 afr[2];
    #pragma unroll
    for (int fi = 0; fi < 2; ++fi){
      f32x4 f0 = {0.f,0.f,0.f,0.f}, f1 = {0.f,0.f,0.f,0.f};
      if (k0 < 784){
        const f32x4* p = (const f32x4*)(xp0 + fi*(16*784) + k0);
        f0 = p[0]; f1 = p[1];
      }
      u32x4 pk = { f2bf_pk(f0[0], f0[1]), f2bf_pk(f0[2], f0[3]),
                   f2bf_pk(f1[0], f1[1]), f2bf_pk(f1[2], f1[3]) };
      afr[fi] = __builtin_bit_cast(bf16x8, pk);
    }
    bf16x8 bfr[2];
    #pragma unroll
    for (int fj = 0; fj < 2; ++fj)
      bfr[fj] = *(const bf16x8*)(wb0 + fj*(16*800) + k0);
    #pragma unroll
    for (int fi = 0; fi < 2; ++fi)
      #pragma unroll
      for (int fj = 0; fj < 2; ++fj)
        acc[fi][fj] = __builtin_amdgcn_mfma_f32_16x16x32_bf16(afr[fi], bfr[fj], acc[fi][fj], 0, 0, 0);
  }

  #pragma unroll
  for (int fi = 0; fi < 2; ++fi){
    #pragma unroll
    for (int fj = 0; fj < 2; ++fj){
      const int col = wc*32 + fj*16 + lr;
      const int r0  = wr*32 + fi*16 + lkg*4;
      const float bc = bcomb[col];
      #pragma unroll
      for (int j = 0; j < 4; ++j)
        vlds[r0 + j][col] = acc[fi][fj][j] + bc;
    }
  }
  __syncthreads();

  const int row = tid >> 2, p4 = tid & 3;
  {
    f32x4 rv[4];
    float* vptr = &vlds[row][p4*16];
    #pragma unroll
    for (int i = 0; i < 4; ++i) rv[i] = ((const f32x4*)vptr)[i];
    float ssq = 0.f;
    #pragma unroll
    for (int i = 0; i < 4; ++i)
      ssq += rv[i][0]*rv[i][0] + rv[i][1]*rv[i][1] + rv[i][2]*rv[i][2] + rv[i][3]*rv[i][3];
    ssq += __shfl_xor(ssq, 1); ssq += __shfl_xor(ssq, 2);
    const float fac = radial_factor(ssq, 1.0f, 1.0f);
    #pragma unroll
    for (int i = 0; i < 4; ++i){ rv[i] *= fac; ((f32x4*)vptr)[i] = rv[i]; }
  }
  __syncthreads();
  {
    const int og = p4;
    float a0o[8];
    #pragma unroll
    for (int j = 0; j < 8; ++j) a0o[j] = cb0a[og*8 + j];
    for (int k = 0; k < 64; k += 4){
      f32x4 vtv = *(const f32x4*)&vlds[row][k];
      f32x4 mm = *(const f32x4*)&cmb0[k];
      #pragma unroll
      for (int u = 0; u < 4; ++u){
        const float vc = 2.f*vtv[u] - mm[u];
        const f32x4* wp = (const f32x4*)(W0aT + (size_t)(k+u)*32 + og*8);
        f32x4 w0 = wp[0], w1 = wp[1];
        #pragma unroll
        for (int j = 0; j < 4; ++j){ a0o[j] += w0[j]*vc; a0o[4+j] += w1[j]*vc; }
      }
    }
    #pragma unroll
    for (int j = 0; j < 8; ++j) g0[row][og*8 + j] = gelu_f(a0o[j]);
  }
  __syncthreads();
  {
    const int o1 = p4;
    float a1 = cb0b[o1];
    for (int k = 0; k < 32; k += 4){
      f32x4 gg = *(const f32x4*)&g0[row][k];
      f32x4 ww = *(const f32x4*)&cW0b[o1][k];
      a1 += gg[0]*ww[0] + gg[1]*ww[1] + gg[2]*ww[2] + gg[3]*ww[3];
    }
    float ss1 = a1*a1;
    ss1 += __shfl_xor(ss1, 1); ss1 += __shfl_xor(ss1, 2);
    const float f1v = radial_factor(ss1, 0.8f, 0.8f);
    const float vt1 = a1*f1v;
    vlds[row][64 + o1] = vt1;
    vlds[row][68 + o1] = 2.f*vt1 - cmb1[o1];
  }
  __syncthreads();
  {
    const f32x4 vc1 = *(const f32x4*)&vlds[row][68];
    #pragma unroll
    for (int j = 0; j < 4; ++j){
      const int o = p4*4 + j;
      float s1 = cb1a[o] + cW1aE[o][0]*vc1[0] + cW1aE[o][1]*vc1[1]
                         + cW1aE[o][2]*vc1[2] + cW1aE[o][3]*vc1[3];
      g1[row][o] = gelu_f(s1);
    }
  }
  __syncthreads();
  {
    float v2[8]; float ss2 = 0.f;
    #pragma unroll
    for (int j = 0; j < 8; ++j){
      const int o = p4*8 + j;
      float s = cb1b[o];
      for (int k = 0; k < 16; k += 4){
        f32x4 gg = *(const f32x4*)&g1[row][k];
        f32x4 ww = *(const f32x4*)&cW1b[o][k];
        s += gg[0]*ww[0] + gg[1]*ww[1] + gg[2]*ww[2] + gg[3]*ww[3];
      }
      v2[j] = s; ss2 += s*s;
    }
    ss2 += __shfl_xor(ss2, 1); ss2 += __shfl_xor(ss2, 2);
    const float f2v = radial_factor(ss2, 1.2f, 0.6f);
    #pragma unroll
    for (int j = 0; j < 8; ++j) vt2[row][p4*8 + j] = v2[j]*f2v;
  }
  __syncthreads();
  for (int idx = tid; idx < 640; idx += 256){
    const int r6 = idx/10, o = idx - r6*10;
    float s = cbout[o];
    const float* wrow = &cWout[o][0];
    const float* vrow = &vlds[r6][0];
    for (int k = 0; k < 68; k += 4){
      f32x4 a = *(const f32x4*)(vrow + k);
      f32x4 b = *(const f32x4*)(wrow + k);
      s += a[0]*b[0] + a[1]*b[1] + a[2]*b[2] + a[3]*b[3];
    }
    const float* v2row = &vt2[r6][0];
    for (int k = 0; k < 32; k += 4){
      f32x4 a = *(const f32x4*)(v2row + k);
      f32x4 b = *(const f32x4*)(wrow + 68 + k);
      s += a[0]*b[0] + a[1]*b[1] + a[2]*b[2] + a[3]*b[3];
    }
    out[(rowBase + (size_t)r6)*10 + o] = s;
  }
}

extern "C" void kernel_launch(void* const* d_in, const int* in_sizes, int n_in,
                              void* d_out, int out_size, void* d_ws, size_t ws_size,
                              hipStream_t stream)
{
  (void)n_in; (void)out_size;
  const float* x      = (const float*)d_in[0];
  const float* W_in   = (const float*)d_in[1];
  const float* b_in   = (const float*)d_in[2];
  const float* W_tan  = (const float*)d_in[3];
  const float* b_tan  = (const float*)d_in[4];
  const float* bp0    = (const float*)d_in[5];
  const float* bp1    = (const float*)d_in[6];
  /* bp2 = d_in[7] — dead in reference */
  const float* A_rot  = (const float*)d_in[8];
  const float* p_quat = (const float*)d_in[9];
  const float* q_quat = (const float*)d_in[10];
  const float* W0a    = (const float*)d_in[11];
  const float* b0a    = (const float*)d_in[12];
  const float* W0b    = (const float*)d_in[13];
  const float* b0b    = (const float*)d_in[14];
  const float* W1a    = (const float*)d_in[15];
  const float* b1a    = (const float*)d_in[16];
  const float* W1b    = (const float*)d_in[17];
  const float* b1b    = (const float*)d_in[18];
  const float* W_out  = (const float*)d_in[19];
  const float* b_out  = (const float*)d_in[20];

  char* ws = (char*)d_ws;
  unsigned short* Wc = (unsigned short*)(ws + WS_WC);
  float* bcomb = (float*)(ws + WS_BCOMB);
  float* W0aE  = (float*)(ws + WS_W0AE);
  float* brot0 = (float*)(ws + WS_BROT0);
  float* bown0 = (float*)(ws + WS_BOWN0);
  float* W0aT  = (float*)(ws + WS_W0AT);
  float* mb0   = (float*)(ws + WS_MB0);
  float* mb1   = (float*)(ws + WS_MB1);
  float* W1aE  = (float*)(ws + WS_W1AE);
  float* vbuf  = (float*)(ws + WS_V);

  const int Brows = in_sizes[0] / 784;
  const int nblk  = Brows / 64;
  const size_t ws_needed = (size_t)WS_V + (size_t)Brows * 64 * 4;

  prep_a<<<60, 256, 0, stream>>>(W_in, b_in, W_tan, b_tan, A_rot, W0a, bp0,
                                 Wc, bcomb, W0aE, brot0, bown0);
  prep_small<<<1, 256, 0, stream>>>(bp1, p_quat, q_quat, b0a, W0b, b0b, W1a,
                                    W0aE, brot0, bown0, W0aT, mb0, mb1, W1aE);
  if (ws_size >= ws_needed){
    gemm_v<<<nblk, 256, 0, stream>>>(x, Wc, bcomb, vbuf);
    row_phase<<<nblk, 256, 0, stream>>>(vbuf, W0aT, mb0, mb1, W1aE,
                                        b0a, W0b, b0b, b1a, W1b, b1b,
                                        W_out, b_out, (float*)d_out);
  } else {
    fused_main<<<nblk, 256, 0, stream>>>(x, Wc, bcomb, W0aT, mb0, mb1, W1aE,
                                         b0a, W0b, b0b, b1a, W1b, b1b,
                                         W_out, b_out, (float*)d_out);
  }
}

// Round 3
// 102.499 us; speedup vs baseline: 2.0731x; 1.9001x over previous
//
#include <hip/hip_runtime.h>
#include <hip/hip_bf16.h>

typedef __attribute__((ext_vector_type(4))) float f32x4;
typedef __attribute__((ext_vector_type(2))) unsigned int u32x2;
typedef __attribute__((ext_vector_type(4))) unsigned int u32x4;
typedef __attribute__((ext_vector_type(8))) short bf16x8;

#define EPSF 1e-7f

// radial factor of logmap0(projx(expmap0(v*s, c), c), c)/s  applied to v, given sumsq(v)
__device__ __forceinline__ float radial_factor(float sumsq, float c, float s){
  float sc = sqrtf(c);
  float nv = sqrtf(sumsq);
  float nu = fmaxf(s*nv, EPSF);            // norm used in expmap0 (of v*s)
  float th = tanhf(sc*nu);
  float r1 = th/sc;                        // radius after expmap0
  float maxn = (1.0f - 1e-5f)/sc;
  float r2 = fminf(r1, maxn);              // radius after projx
  float n1 = fmaxf(r2, EPSF);              // norm recomputed in logmap0
  float a  = fminf(sc*n1, 1.0f - 1e-7f);
  float r3 = 0.5f*logf((1.0f + a)/(1.0f - a));   // artanh(a)
  return r3*r2/(sc*n1*nu);
}

__device__ __forceinline__ float gelu_f(float x){
  return 0.5f*x*(1.0f + erff(x*0.70710678118654752f));
}

__device__ __forceinline__ unsigned f2bf1(float f){   // RNE f32->bf16 (low 16 bits)
  unsigned u = __float_as_uint(f);
  return (u + 0x7FFFu + ((u>>16)&1u)) >> 16;
}
__device__ __forceinline__ unsigned f2bf_pk(float lo, float hi){
  unsigned ul = f2bf1(lo);
  unsigned uh = __float_as_uint(hi);
  uh = (uh + 0x7FFFu + ((uh>>16)&1u)) & 0xFFFF0000u;
  return ul | uh;
}

// ---------------- workspace layout (bytes) ----------------
#define WS_WC     0          // bf16 [64][800]
#define WS_BCOMB  204800     // f32 [64]
#define WS_W0AE   205056     // f32 [32][64]
#define WS_BROT0  213248     // f32 [5][64]
#define WS_BOWN0  214528     // f32 [5][64]
#define WS_W0AT   215808     // f32 [64][32]
#define WS_MB0    224000     // f32 [64]
#define WS_MB1    224256     // f32 [4]
#define WS_W1AE   224272     // f32 [16][4]
#define WS_V      225280     // f32 [B][64]

// ============ prep A: W_comb (blocks 0..49) + exp row-actions (blocks 50..59) ============
__global__ __launch_bounds__(256) void prep_a(
    const float* __restrict__ W_in, const float* __restrict__ b_in,
    const float* __restrict__ W_tan, const float* __restrict__ b_tan,
    const float* __restrict__ A_rot, const float* __restrict__ W0a,
    const float* __restrict__ bp0,
    unsigned short* __restrict__ Wc, float* __restrict__ bcomb,
    float* __restrict__ W0aE, float* __restrict__ brot0, float* __restrict__ bown0)
{
  __shared__ __align__(16) float Al[64][68];
  __shared__ __align__(16) float ST[64][68];   // ST[j][m] = S[m][j], S = A - A^T
  const int bid = blockIdx.x, t = threadIdx.x;

  if (bid < 50){
    if (bid == 0 && t < 64){
      float s = b_tan[t];
      for (int j = 0; j < 128; ++j) s += b_in[j]*W_tan[t*128+j];
      bcomb[t] = s;
    }
    const int g4 = bid*256 + t;              // 0..12799
    const int n = g4/200, k4 = (g4 - n*200)*4;
    f32x4 s = {0.f,0.f,0.f,0.f};
    if (k4 < 784){
      for (int j = 0; j < 128; ++j){
        float wt = W_tan[n*128+j];
        f32x4 wi = *(const f32x4*)(W_in + j*784 + k4);
        s += wt*wi;
      }
    }
    u32x2 st = { f2bf_pk(s[0], s[1]), f2bf_pk(s[2], s[3]) };
    *(u32x2*)(Wc + n*800 + k4) = st;
  } else {
    for (int m = t; m < 4096; m += 256){
      int r = m >> 6, c = m & 63;
      Al[r][c] = A_rot[m];
    }
    __syncthreads();
    for (int m = t; m < 4096; m += 256){
      int r = m >> 6, c = m & 63;
      ST[r][c] = Al[c][r] - Al[r][c];
    }
    __syncthreads();
    const int wv = t >> 6, lane = t & 63;
    const int row = (bid - 50)*4 + wv;      // 0..39, active < 37
    if (row < 37){
      float v, sgn;
      if (row < 32){ v = W0a[row*64 + lane]; sgn = 1.f; }
      else {
        const int r = row - 32;
        float b = bp0[r*64 + lane];
        float ssq = b*b;
        #pragma unroll
        for (int d = 1; d < 64; d <<= 1) ssq += __shfl_xor(ssq, d);
        float fc = radial_factor(ssq, 1.0f, 1.0f);
        v = b*fc;
        bown0[r*64 + lane] = v;
        sgn = -1.f;
      }
      float acc = v;
      for (int k = 1; k <= 12; ++k){
        const float coef = sgn/(float)k;
        float nv = 0.f;
        #pragma unroll
        for (int m = 0; m < 64; m += 4){
          f32x4 s4 = *(const f32x4*)&ST[lane][m];
          nv += __int_as_float(__builtin_amdgcn_readlane(__float_as_int(v), m+0))*s4[0];
          nv += __int_as_float(__builtin_amdgcn_readlane(__float_as_int(v), m+1))*s4[1];
          nv += __int_as_float(__builtin_amdgcn_readlane(__float_as_int(v), m+2))*s4[2];
          nv += __int_as_float(__builtin_amdgcn_readlane(__float_as_int(v), m+3))*s4[3];
        }
        nv *= coef;
        v = nv; acc += nv;
      }
      if (row < 32) W0aE[row*64 + lane] = acc;
      else          brot0[(row-32)*64 + lane] = acc;
    }
  }
}

// ============ prep B: small folds (1 block x 256) ============
__global__ __launch_bounds__(256) void prep_small(
    const float* __restrict__ bp1,
    const float* __restrict__ p_quat, const float* __restrict__ q_quat,
    const float* __restrict__ b0a, const float* __restrict__ W0b, const float* __restrict__ b0b,
    const float* __restrict__ W1a,
    const float* __restrict__ W0aE, const float* __restrict__ brot0, const float* __restrict__ bown0,
    float* __restrict__ W0aT, float* __restrict__ mb0, float* __restrict__ mb1,
    float* __restrict__ W1aE)
{
  __shared__ float g[5][32];
  __shared__ float c1[5][4];
  __shared__ float fac1[3];
  __shared__ float Mq[4][4];
  const int t = threadIdx.x;

  for (int i = t; i < 2048; i += 256){
    int o = i >> 6, k = i & 63;
    W0aT[k*32 + o] = W0aE[i];
  }
  if (t < 64){
    float s = 0.f;
    for (int r = 0; r < 5; ++r) s += bown0[r*64 + t];
    mb0[t] = s * 0.2f;
  }
  if (t < 160){
    int r = t >> 5, o = t & 31;
    float s = b0a[o];
    for (int k = 0; k < 64; ++k) s += brot0[r*64+k]*W0aE[o*64+k];
    g[r][o] = gelu_f(s);
  }
  if (t >= 192 && t < 195){
    int r = t - 192;
    float ssq = 0.f;
    for (int j = 0; j < 4; ++j){ float b = bp1[r*4+j]; ssq += b*b; }
    fac1[r] = radial_factor(ssq, 0.8f, 1.0f);
  }
  if (t == 224){
    float pw=p_quat[0],px=p_quat[1],py=p_quat[2],pz=p_quat[3];
    float n1 = sqrtf(pw*pw+px*px+py*py+pz*pz) + EPSF;
    pw/=n1; px/=n1; py/=n1; pz/=n1;
    float qw=q_quat[0],qx=q_quat[1],qy=q_quat[2],qz=q_quat[3];
    float n2 = sqrtf(qw*qw+qx*qx+qy*qy+qz*qz) + EPSF;
    qw/=n2; qx/=n2; qy/=n2; qz/=n2;
    float Lp[4][4] = {{pw,-px,-py,-pz},{px,pw,-pz,py},{py,pz,pw,-px},{pz,-py,px,pw}};
    float Rq[4][4] = {{qw,-qx,-qy,-qz},{qx,qw,qz,-qy},{qy,-qz,qw,qx},{qz,qy,-qx,qw}};
    #pragma unroll
    for (int i = 0; i < 4; ++i)
      #pragma unroll
      for (int k = 0; k < 4; ++k){
        float s = 0.f;
        #pragma unroll
        for (int m = 0; m < 4; ++m) s += Rq[i][m]*Lp[m][k];
        Mq[i][k] = s;
      }
  }
  __syncthreads();
  if (t < 20){
    int r = t >> 2, o = t & 3;
    float s = b0b[o];
    for (int k = 0; k < 32; ++k) s += g[r][k]*W0b[o*32+k];
    c1[r][o] = s;
  }
  __syncthreads();
  if (t < 4){
    float s = 0.f;
    for (int r = 0; r < 3; ++r) s += bp1[r*4+t]*fac1[r];
    for (int r = 0; r < 5; ++r) s += c1[r][t];
    mb1[t] = s * 0.125f;
  }
  if (t >= 64 && t < 128){
    int i = t - 64, o = i >> 2, kq = i & 3;
    float s = 0.f;
    #pragma unroll
    for (int j = 0; j < 4; ++j) s += W1a[o*4+j]*Mq[j][kq];
    W1aE[o*4+kq] = s;
  }
}

// ============ kernel 1: v = x @ Wc^T + bcomb (lean, high-occupancy) ============
__global__ __launch_bounds__(256, 4) void gemm_v(
    const float* __restrict__ x,
    const unsigned short* __restrict__ Wc,
    const float* __restrict__ bcomb,
    float* __restrict__ v)
{
  __shared__ __align__(16) float vt[64][68];
  const int tid  = threadIdx.x;
  const int lane = tid & 63;
  const int w    = tid >> 6;
  const int wr   = w >> 1, wc = w & 1;
  const int lr   = lane & 15, lkg = lane >> 4;
  const size_t rowBase = (size_t)blockIdx.x * 64;
  const float* xp0 = x + (rowBase + (size_t)(wr*32 + lr)) * 784;
  const unsigned short* wb0 = Wc + (size_t)(wc*32 + lr) * 800;

  f32x4 acc[2][2] = {};
  f32x4 f[4];
  {
    const int k0 = lkg*8;
    const f32x4* p0 = (const f32x4*)(xp0 + k0);
    const f32x4* p1 = (const f32x4*)(xp0 + 16*784 + k0);
    f[0] = p0[0]; f[1] = p0[1]; f[2] = p1[0]; f[3] = p1[1];
  }
  for (int kk = 0; kk < 25; ++kk){
    const int k0 = kk*32 + lkg*8;
    f32x4 fn[4] = {{0.f,0.f,0.f,0.f},{0.f,0.f,0.f,0.f},{0.f,0.f,0.f,0.f},{0.f,0.f,0.f,0.f}};
    const int k1 = k0 + 32;
    if (kk < 24 && k1 < 784){
      const f32x4* p0 = (const f32x4*)(xp0 + k1);
      const f32x4* p1 = (const f32x4*)(xp0 + 16*784 + k1);
      fn[0] = p0[0]; fn[1] = p0[1]; fn[2] = p1[0]; fn[3] = p1[1];
    }
    u32x4 pk0 = { f2bf_pk(f[0][0], f[0][1]), f2bf_pk(f[0][2], f[0][3]),
                  f2bf_pk(f[1][0], f[1][1]), f2bf_pk(f[1][2], f[1][3]) };
    u32x4 pk1 = { f2bf_pk(f[2][0], f[2][1]), f2bf_pk(f[2][2], f[2][3]),
                  f2bf_pk(f[3][0], f[3][1]), f2bf_pk(f[3][2], f[3][3]) };
    bf16x8 afr0 = __builtin_bit_cast(bf16x8, pk0);
    bf16x8 afr1 = __builtin_bit_cast(bf16x8, pk1);
    bf16x8 bfr0 = *(const bf16x8*)(wb0 + k0);
    bf16x8 bfr1 = *(const bf16x8*)(wb0 + 16*800 + k0);
    acc[0][0] = __builtin_amdgcn_mfma_f32_16x16x32_bf16(afr0, bfr0, acc[0][0], 0, 0, 0);
    acc[0][1] = __builtin_amdgcn_mfma_f32_16x16x32_bf16(afr0, bfr1, acc[0][1], 0, 0, 0);
    acc[1][0] = __builtin_amdgcn_mfma_f32_16x16x32_bf16(afr1, bfr0, acc[1][0], 0, 0, 0);
    acc[1][1] = __builtin_amdgcn_mfma_f32_16x16x32_bf16(afr1, bfr1, acc[1][1], 0, 0, 0);
    f[0] = fn[0]; f[1] = fn[1]; f[2] = fn[2]; f[3] = fn[3];
  }

  // LDS transpose for coalesced v stores
  #pragma unroll
  for (int fi = 0; fi < 2; ++fi){
    #pragma unroll
    for (int fj = 0; fj < 2; ++fj){
      const int col = wc*32 + fj*16 + lr;
      const int r0  = wr*32 + fi*16 + lkg*4;
      const float bc = bcomb[col];
      #pragma unroll
      for (int j = 0; j < 4; ++j)
        vt[r0 + j][col] = acc[fi][fj][j] + bc;
    }
  }
  __syncthreads();
  const int row = tid >> 2, seg = tid & 3;
  float* dst = v + (rowBase + (size_t)row)*64 + seg*16;
  const float* src = &vt[row][seg*16];
  #pragma unroll
  for (int i = 0; i < 4; ++i)
    ((f32x4*)dst)[i] = ((const f32x4*)src)[i];
}

// ============ kernel 2: row phase (radial + MLP chain + head) ============
// All weights staged in LDS; no global loads inside compute loops -> no
// VGPR blow-up from hoisted global loads (R2 spill root-cause fix).
__global__ __launch_bounds__(256, 4) void row_phase(
    const float* __restrict__ v,
    const float* __restrict__ W0aT,
    const float* __restrict__ mb0g, const float* __restrict__ mb1g,
    const float* __restrict__ W1aEg,
    const float* __restrict__ b0a, const float* __restrict__ W0b, const float* __restrict__ b0b,
    const float* __restrict__ b1a, const float* __restrict__ W1b, const float* __restrict__ b1b,
    const float* __restrict__ Wout, const float* __restrict__ bout,
    float* __restrict__ out)
{
  __shared__ __align__(16) float vlds[64][76];   // vt0 [0..64), vt1 [64..68), vc1 [68..72)
  __shared__ __align__(16) float gv[64][36];     // g0 during R2/R3, vt2 during R5/R6
  __shared__ __align__(16) float g1[64][20];
  __shared__ __align__(16) float cW0aT[64][32];  // [k][o]
  __shared__ __align__(16) float cmb0[64];
  __shared__ __align__(16) float cW0b[4][32];
  __shared__ __align__(16) float cW1b[32][16];
  __shared__ __align__(16) float cWout[10][100];
  __shared__ __align__(16) float cW1aE[16][4];
  __shared__ float cb0a[32], cb0b[4], cmb1[4], cb1a[16], cb1b[32], cbout[12];

  const int tid = threadIdx.x;
  const size_t rowBase = (size_t)blockIdx.x * 64;

  // load v tile (coalesced)
  for (int i = tid; i < 1024; i += 256){
    const int r = i >> 4, seg = i & 15;
    *(f32x4*)&vlds[r][seg*4] = *(const f32x4*)(v + (rowBase + (size_t)r)*64 + seg*4);
  }
  // stage weights/constants into LDS
  for (int i = tid; i < 2048; i += 256) ((float*)0, cW0aT[i>>5][i&31] = W0aT[i]);
  if (tid < 64)  cmb0[tid] = mb0g[tid];
  if (tid < 32)  cb0a[tid] = b0a[tid];
  if (tid < 128) ((float*)cW0b)[tid] = W0b[tid];
  if (tid < 4)   { cb0b[tid] = b0b[tid]; cmb1[tid] = mb1g[tid]; }
  if (tid < 64)  ((float*)cW1aE)[tid] = W1aEg[tid];
  if (tid < 16)  cb1a[tid] = b1a[tid];
  if (tid < 32)  cb1b[tid] = b1b[tid];
  if (tid < 10)  cbout[tid] = bout[tid];
  for (int i = tid; i < 512; i += 256)  ((float*)cW1b)[i] = W1b[i];
  for (int i = tid; i < 1000; i += 256) ((float*)cWout)[i] = Wout[i];
  __syncthreads();

  const int row = tid >> 2, p4 = tid & 3;

  // R1: v_tan0 = radial(v)  (in place)
  {
    f32x4 rv[4];
    float* vptr = &vlds[row][p4*16];
    #pragma unroll
    for (int i = 0; i < 4; ++i) rv[i] = ((const f32x4*)vptr)[i];
    float ssq = 0.f;
    #pragma unroll
    for (int i = 0; i < 4; ++i)
      ssq += rv[i][0]*rv[i][0] + rv[i][1]*rv[i][1] + rv[i][2]*rv[i][2] + rv[i][3]*rv[i][3];
    ssq += __shfl_xor(ssq, 1); ssq += __shfl_xor(ssq, 2);
    const float fac = radial_factor(ssq, 1.0f, 1.0f);
    #pragma unroll
    for (int i = 0; i < 4; ++i){ rv[i] *= fac; ((f32x4*)vptr)[i] = rv[i]; }
  }
  __syncthreads();

  // R2: a0 = W0aE @ (2*vt0 - mb0) + b0a ; g0 = gelu(a0)   (8 outputs/thread)
  {
    const int og = p4;
    float a0o[8];
    #pragma unroll
    for (int j = 0; j < 8; ++j) a0o[j] = cb0a[og*8 + j];
    #pragma unroll 4
    for (int k = 0; k < 64; k += 4){
      f32x4 vtv = *(const f32x4*)&vlds[row][k];
      f32x4 mm = *(const f32x4*)&cmb0[k];
      #pragma unroll
      for (int u = 0; u < 4; ++u){
        const float vc = 2.f*vtv[u] - mm[u];
        const f32x4* wp = (const f32x4*)&cW0aT[k+u][og*8];
        f32x4 w0 = wp[0], w1 = wp[1];
        #pragma unroll
        for (int j = 0; j < 4; ++j){ a0o[j] += w0[j]*vc; a0o[4+j] += w1[j]*vc; }
      }
    }
    #pragma unroll
    for (int j = 0; j < 8; ++j) gv[row][og*8 + j] = gelu_f(a0o[j]);
  }
  __syncthreads();

  // R3: v1 = W0b@g0 + b0b (1 comp/thread); v_tan1, v_comb1
  {
    const int o1 = p4;
    float a1 = cb0b[o1];
    #pragma unroll
    for (int k = 0; k < 32; k += 4){
      f32x4 gg = *(const f32x4*)&gv[row][k];
      f32x4 ww = *(const f32x4*)&cW0b[o1][k];
      a1 += gg[0]*ww[0] + gg[1]*ww[1] + gg[2]*ww[2] + gg[3]*ww[3];
    }
    float ss1 = a1*a1;
    ss1 += __shfl_xor(ss1, 1); ss1 += __shfl_xor(ss1, 2);
    const float f1v = radial_factor(ss1, 0.8f, 0.8f);
    const float vt1 = a1*f1v;
    vlds[row][64 + o1] = vt1;
    vlds[row][68 + o1] = 2.f*vt1 - cmb1[o1];
  }
  __syncthreads();

  // R4: a1 = W1aE @ vc1 + b1a ; g1 = gelu  (4 outputs/thread)
  {
    const f32x4 vc1 = *(const f32x4*)&vlds[row][68];
    #pragma unroll
    for (int j = 0; j < 4; ++j){
      const int o = p4*4 + j;
      float s1 = cb1a[o] + cW1aE[o][0]*vc1[0] + cW1aE[o][1]*vc1[1]
                         + cW1aE[o][2]*vc1[2] + cW1aE[o][3]*vc1[3];
      g1[row][o] = gelu_f(s1);
    }
  }
  __syncthreads();

  // R5: v2 = W1b@g1 + b1b (8/thread); v_tan2 -> gv
  {
    float v2[8]; float ss2 = 0.f;
    #pragma unroll
    for (int j = 0; j < 8; ++j){
      const int o = p4*8 + j;
      float s = cb1b[o];
      #pragma unroll
      for (int k = 0; k < 16; k += 4){
        f32x4 gg = *(const f32x4*)&g1[row][k];
        f32x4 ww = *(const f32x4*)&cW1b[o][k];
        s += gg[0]*ww[0] + gg[1]*ww[1] + gg[2]*ww[2] + gg[3]*ww[3];
      }
      v2[j] = s; ss2 += s*s;
    }
    ss2 += __shfl_xor(ss2, 1); ss2 += __shfl_xor(ss2, 2);
    const float f2v = radial_factor(ss2, 1.2f, 0.6f);
    #pragma unroll
    for (int j = 0; j < 8; ++j) gv[row][p4*8 + j] = v2[j]*f2v;
  }
  __syncthreads();

  // R6: out = W_out @ concat(vt0, vt1, vt2) + b_out
  for (int idx = tid; idx < 640; idx += 256){
    const int r6 = idx/10, o = idx - r6*10;
    float s = cbout[o];
    const float* wrow = &cWout[o][0];
    const float* vrow = &vlds[r6][0];
    #pragma unroll 4
    for (int k = 0; k < 68; k += 4){
      f32x4 a = *(const f32x4*)(vrow + k);
      f32x4 b = *(const f32x4*)(wrow + k);
      s += a[0]*b[0] + a[1]*b[1] + a[2]*b[2] + a[3]*b[3];
    }
    const float* v2row = &gv[r6][0];
    #pragma unroll 4
    for (int k = 0; k < 32; k += 4){
      f32x4 a = *(const f32x4*)(v2row + k);
      f32x4 b = *(const f32x4*)(wrow + 68 + k);
      s += a[0]*b[0] + a[1]*b[1] + a[2]*b[2] + a[3]*b[3];
    }
    out[(rowBase + (size_t)r6)*10 + o] = s;
  }
}

extern "C" void kernel_launch(void* const* d_in, const int* in_sizes, int n_in,
                              void* d_out, int out_size, void* d_ws, size_t ws_size,
                              hipStream_t stream)
{
  (void)n_in; (void)out_size; (void)ws_size;
  const float* x      = (const float*)d_in[0];
  const float* W_in   = (const float*)d_in[1];
  const float* b_in   = (const float*)d_in[2];
  const float* W_tan  = (const float*)d_in[3];
  const float* b_tan  = (const float*)d_in[4];
  const float* bp0    = (const float*)d_in[5];
  const float* bp1    = (const float*)d_in[6];
  /* bp2 = d_in[7] — dead in reference */
  const float* A_rot  = (const float*)d_in[8];
  const float* p_quat = (const float*)d_in[9];
  const float* q_quat = (const float*)d_in[10];
  const float* W0a    = (const float*)d_in[11];
  const float* b0a    = (const float*)d_in[12];
  const float* W0b    = (const float*)d_in[13];
  const float* b0b    = (const float*)d_in[14];
  const float* W1a    = (const float*)d_in[15];
  const float* b1a    = (const float*)d_in[16];
  const float* W1b    = (const float*)d_in[17];
  const float* b1b    = (const float*)d_in[18];
  const float* W_out  = (const float*)d_in[19];
  const float* b_out  = (const float*)d_in[20];

  char* ws = (char*)d_ws;
  unsigned short* Wc = (unsigned short*)(ws + WS_WC);
  float* bcomb = (float*)(ws + WS_BCOMB);
  float* W0aE  = (float*)(ws + WS_W0AE);
  float* brot0 = (float*)(ws + WS_BROT0);
  float* bown0 = (float*)(ws + WS_BOWN0);
  float* W0aT  = (float*)(ws + WS_W0AT);
  float* mb0   = (float*)(ws + WS_MB0);
  float* mb1   = (float*)(ws + WS_MB1);
  float* W1aE  = (float*)(ws + WS_W1AE);
  float* vbuf  = (float*)(ws + WS_V);

  const int Brows = in_sizes[0] / 784;
  const int nblk  = Brows / 64;

  prep_a<<<60, 256, 0, stream>>>(W_in, b_in, W_tan, b_tan, A_rot, W0a, bp0,
                                 Wc, bcomb, W0aE, brot0, bown0);
  prep_small<<<1, 256, 0, stream>>>(bp1, p_quat, q_quat, b0a, W0b, b0b, W1a,
                                    W0aE, brot0, bown0, W0aT, mb0, mb1, W1aE);
  gemm_v<<<nblk, 256, 0, stream>>>(x, Wc, bcomb, vbuf);
  row_phase<<<nblk, 256, 0, stream>>>(vbuf, W0aT, mb0, mb1, W1aE,
                                      b0a, W0b, b0b, b1a, W1b, b1b,
                                      W_out, b_out, (float*)d_out);
}

// Round 4
// 91.992 us; speedup vs baseline: 2.3098x; 1.1142x over previous
//
#include <hip/hip_runtime.h>
#include <hip/hip_bf16.h>

typedef __attribute__((ext_vector_type(4))) float f32x4;
typedef __attribute__((ext_vector_type(2))) unsigned int u32x2;
typedef __attribute__((ext_vector_type(4))) unsigned int u32x4;
typedef __attribute__((ext_vector_type(8))) short bf16x8;

#define EPSF 1e-7f

// radial factor of logmap0(projx(expmap0(v*s, c), c), c)/s  applied to v, given sumsq(v)
__device__ __forceinline__ float radial_factor(float sumsq, float c, float s){
  float sc = sqrtf(c);
  float nv = sqrtf(sumsq);
  float nu = fmaxf(s*nv, EPSF);            // norm used in expmap0 (of v*s)
  float th = tanhf(sc*nu);
  float r1 = th/sc;                        // radius after expmap0
  float maxn = (1.0f - 1e-5f)/sc;
  float r2 = fminf(r1, maxn);              // radius after projx
  float n1 = fmaxf(r2, EPSF);              // norm recomputed in logmap0
  float a  = fminf(sc*n1, 1.0f - 1e-7f);
  float r3 = 0.5f*logf((1.0f + a)/(1.0f - a));   // artanh(a)
  return r3*r2/(sc*n1*nu);
}

__device__ __forceinline__ float gelu_f(float x){
  return 0.5f*x*(1.0f + erff(x*0.70710678118654752f));
}

__device__ __forceinline__ unsigned f2bf1(float f){   // RNE f32->bf16 (low 16 bits)
  unsigned u = __float_as_uint(f);
  return (u + 0x7FFFu + ((u>>16)&1u)) >> 16;
}
__device__ __forceinline__ unsigned f2bf_pk(float lo, float hi){
  unsigned ul = f2bf1(lo);
  unsigned uh = __float_as_uint(hi);
  uh = (uh + 0x7FFFu + ((uh>>16)&1u)) & 0xFFFF0000u;
  return ul | uh;
}

// ---------------- workspace layout (bytes) ----------------
#define WS_WC     0          // bf16 [64][800]
#define WS_BCOMB  204800     // f32 [64]
#define WS_W0AE   205056     // f32 [32][64]
#define WS_BROT0  213248     // f32 [5][64]
#define WS_BOWN0  214528     // f32 [5][64]
#define WS_W0AT   215808     // f32 [64][32]
#define WS_MB0    224000     // f32 [64]
#define WS_MB1    224256     // f32 [4]
#define WS_W1AE   224272     // f32 [16][4]

// ============ prep A: W_comb (blocks 0..49) + exp row-actions (blocks 50..59) ============
__global__ __launch_bounds__(256) void prep_a(
    const float* __restrict__ W_in, const float* __restrict__ b_in,
    const float* __restrict__ W_tan, const float* __restrict__ b_tan,
    const float* __restrict__ A_rot, const float* __restrict__ W0a,
    const float* __restrict__ bp0,
    unsigned short* __restrict__ Wc, float* __restrict__ bcomb,
    float* __restrict__ W0aE, float* __restrict__ brot0, float* __restrict__ bown0)
{
  __shared__ __align__(16) float Al[64][68];
  __shared__ __align__(16) float ST[64][68];   // ST[j][m] = S[m][j], S = A - A^T
  const int bid = blockIdx.x, t = threadIdx.x;

  if (bid < 50){
    if (bid == 0 && t < 64){
      float s = b_tan[t];
      for (int j = 0; j < 128; ++j) s += b_in[j]*W_tan[t*128+j];
      bcomb[t] = s;
    }
    const int g4 = bid*256 + t;              // 0..12799
    const int n = g4/200, k4 = (g4 - n*200)*4;
    f32x4 s = {0.f,0.f,0.f,0.f};
    if (k4 < 784){
      for (int j = 0; j < 128; ++j){
        float wt = W_tan[n*128+j];
        f32x4 wi = *(const f32x4*)(W_in + j*784 + k4);
        s += wt*wi;
      }
    }
    u32x2 st = { f2bf_pk(s[0], s[1]), f2bf_pk(s[2], s[3]) };
    *(u32x2*)(Wc + n*800 + k4) = st;
  } else {
    for (int m = t; m < 4096; m += 256){
      int r = m >> 6, c = m & 63;
      Al[r][c] = A_rot[m];
    }
    __syncthreads();
    for (int m = t; m < 4096; m += 256){
      int r = m >> 6, c = m & 63;
      ST[r][c] = Al[c][r] - Al[r][c];
    }
    __syncthreads();
    const int wv = t >> 6, lane = t & 63;
    const int row = (bid - 50)*4 + wv;      // 0..39, active < 37
    if (row < 37){
      float v, sgn;
      if (row < 32){ v = W0a[row*64 + lane]; sgn = 1.f; }
      else {
        const int r = row - 32;
        float b = bp0[r*64 + lane];
        float ssq = b*b;
        #pragma unroll
        for (int d = 1; d < 64; d <<= 1) ssq += __shfl_xor(ssq, d);
        float fc = radial_factor(ssq, 1.0f, 1.0f);
        v = b*fc;
        bown0[r*64 + lane] = v;
        sgn = -1.f;
      }
      float acc = v;
      for (int k = 1; k <= 12; ++k){
        const float coef = sgn/(float)k;
        float nv = 0.f;
        #pragma unroll
        for (int m = 0; m < 64; m += 4){
          f32x4 s4 = *(const f32x4*)&ST[lane][m];
          nv += __int_as_float(__builtin_amdgcn_readlane(__float_as_int(v), m+0))*s4[0];
          nv += __int_as_float(__builtin_amdgcn_readlane(__float_as_int(v), m+1))*s4[1];
          nv += __int_as_float(__builtin_amdgcn_readlane(__float_as_int(v), m+2))*s4[2];
          nv += __int_as_float(__builtin_amdgcn_readlane(__float_as_int(v), m+3))*s4[3];
        }
        nv *= coef;
        v = nv; acc += nv;
      }
      if (row < 32) W0aE[row*64 + lane] = acc;
      else          brot0[(row-32)*64 + lane] = acc;
    }
  }
}

// ============ prep B: small folds (1 block x 256) ============
__global__ __launch_bounds__(256) void prep_small(
    const float* __restrict__ bp1,
    const float* __restrict__ p_quat, const float* __restrict__ q_quat,
    const float* __restrict__ b0a, const float* __restrict__ W0b, const float* __restrict__ b0b,
    const float* __restrict__ W1a,
    const float* __restrict__ W0aE, const float* __restrict__ brot0, const float* __restrict__ bown0,
    float* __restrict__ W0aT, float* __restrict__ mb0, float* __restrict__ mb1,
    float* __restrict__ W1aE)
{
  __shared__ float g[5][32];
  __shared__ float c1[5][4];
  __shared__ float fac1[3];
  __shared__ float Mq[4][4];
  const int t = threadIdx.x;

  for (int i = t; i < 2048; i += 256){
    int o = i >> 6, k = i & 63;
    W0aT[k*32 + o] = W0aE[i];
  }
  if (t < 64){
    float s = 0.f;
    for (int r = 0; r < 5; ++r) s += bown0[r*64 + t];
    mb0[t] = s * 0.2f;
  }
  if (t < 160){
    int r = t >> 5, o = t & 31;
    float s = b0a[o];
    for (int k = 0; k < 64; ++k) s += brot0[r*64+k]*W0aE[o*64+k];
    g[r][o] = gelu_f(s);
  }
  if (t >= 192 && t < 195){
    int r = t - 192;
    float ssq = 0.f;
    for (int j = 0; j < 4; ++j){ float b = bp1[r*4+j]; ssq += b*b; }
    fac1[r] = radial_factor(ssq, 0.8f, 1.0f);
  }
  if (t == 224){
    float pw=p_quat[0],px=p_quat[1],py=p_quat[2],pz=p_quat[3];
    float n1 = sqrtf(pw*pw+px*px+py*py+pz*pz) + EPSF;
    pw/=n1; px/=n1; py/=n1; pz/=n1;
    float qw=q_quat[0],qx=q_quat[1],qy=q_quat[2],qz=q_quat[3];
    float n2 = sqrtf(qw*qw+qx*qx+qy*qy+qz*qz) + EPSF;
    qw/=n2; qx/=n2; qy/=n2; qz/=n2;
    float Lp[4][4] = {{pw,-px,-py,-pz},{px,pw,-pz,py},{py,pz,pw,-px},{pz,-py,px,pw}};
    float Rq[4][4] = {{qw,-qx,-qy,-qz},{qx,qw,qz,-qy},{qy,-qz,qw,qx},{qz,qy,-qx,qw}};
    #pragma unroll
    for (int i = 0; i < 4; ++i)
      #pragma unroll
      for (int k = 0; k < 4; ++k){
        float s = 0.f;
        #pragma unroll
        for (int m = 0; m < 4; ++m) s += Rq[i][m]*Lp[m][k];
        Mq[i][k] = s;
      }
  }
  __syncthreads();
  if (t < 20){
    int r = t >> 2, o = t & 3;
    float s = b0b[o];
    for (int k = 0; k < 32; ++k) s += g[r][k]*W0b[o*32+k];
    c1[r][o] = s;
  }
  __syncthreads();
  if (t < 4){
    float s = 0.f;
    for (int r = 0; r < 3; ++r) s += bp1[r*4+t]*fac1[r];
    for (int r = 0; r < 5; ++r) s += c1[r][t];
    mb1[t] = s * 0.125f;
  }
  if (t >= 64 && t < 128){
    int i = t - 64, o = i >> 2, kq = i & 3;
    float s = 0.f;
    #pragma unroll
    for (int j = 0; j < 4; ++j) s += W1a[o*4+j]*Mq[j][kq];
    W1aE[o*4+kq] = s;
  }
}

// ============ fused main: MFMA GEMM -> row phase, all weights in LDS ============
__global__ __launch_bounds__(256, 3) void main_fused(
    const float* __restrict__ x,
    const unsigned short* __restrict__ Wc,
    const float* __restrict__ bcomb,
    const float* __restrict__ W0aT,
    const float* __restrict__ mb0g, const float* __restrict__ mb1g,
    const float* __restrict__ W1aEg,
    const float* __restrict__ b0a, const float* __restrict__ W0b, const float* __restrict__ b0b,
    const float* __restrict__ b1a, const float* __restrict__ W1b, const float* __restrict__ b1b,
    const float* __restrict__ Wout, const float* __restrict__ bout,
    float* __restrict__ out)
{
  __shared__ __align__(16) float vlds[64][76];   // GEMM out / vt0 [0..64), vt1 [64..68), vc1 [68..72)
  __shared__ __align__(16) float gv[64][36];     // g0 during R2/R3, vt2 during R5/R6
  __shared__ __align__(16) float g1[64][20];
  __shared__ __align__(16) float cW0aT[64][32];  // [k][o]
  __shared__ __align__(16) float cmb0[64];
  __shared__ __align__(16) float cW0b[4][32];
  __shared__ __align__(16) float cW1b[32][16];
  __shared__ __align__(16) float cWout[10][100];
  __shared__ __align__(16) float cW1aE[16][4];
  __shared__ float cb0a[32], cb0b[4], cmb1[4], cb1a[16], cb1b[32], cbout[12];

  const int tid = threadIdx.x;
  const size_t rowBase = (size_t)blockIdx.x * 64;

  // ---- stage all row-phase weights into LDS (overlaps with GEMM x loads) ----
  for (int i = tid; i < 2048; i += 256){
    const int k = i >> 5, o = i & 31;
    cW0aT[k][o] = W0aT[k*32 + o];          // coalesced: i contiguous == W0aT linear
  }
  if (tid < 64)  cmb0[tid] = mb0g[tid];
  if (tid < 32)  cb0a[tid] = b0a[tid];
  if (tid < 128) ((float*)cW0b)[tid] = W0b[tid];
  if (tid < 4)   { cb0b[tid] = b0b[tid]; cmb1[tid] = mb1g[tid]; }
  if (tid < 64)  ((float*)cW1aE)[tid] = W1aEg[tid];
  if (tid < 16)  cb1a[tid] = b1a[tid];
  if (tid < 32)  cb1b[tid] = b1b[tid];
  if (tid < 10)  cbout[tid] = bout[tid];
  for (int i = tid; i < 512; i += 256)  ((float*)cW1b)[i] = W1b[i];
  for (int i = tid; i < 1000; i += 256) ((float*)cWout)[i] = Wout[i];

  // ---- GEMM: v[64][64] = x_tile @ Wc^T + bcomb (bf16 MFMA 16x16x32) ----
  const int lane = tid & 63;
  const int w    = tid >> 6;
  const int wr   = w >> 1, wc = w & 1;
  const int lr   = lane & 15, lkg = lane >> 4;
  const float* xp0 = x + (rowBase + (size_t)(wr*32 + lr)) * 784;
  const unsigned short* wb0 = Wc + (size_t)(wc*32 + lr) * 800;

  f32x4 acc[2][2] = {};
  f32x4 f[4];
  {
    const int k0 = lkg*8;
    const f32x4* p0 = (const f32x4*)(xp0 + k0);
    const f32x4* p1 = (const f32x4*)(xp0 + 16*784 + k0);
    f[0] = p0[0]; f[1] = p0[1]; f[2] = p1[0]; f[3] = p1[1];
  }
  for (int kk = 0; kk < 25; ++kk){
    const int k0 = kk*32 + lkg*8;
    f32x4 fn[4] = {{0.f,0.f,0.f,0.f},{0.f,0.f,0.f,0.f},{0.f,0.f,0.f,0.f},{0.f,0.f,0.f,0.f}};
    const int k1 = k0 + 32;
    if (kk < 24 && k1 < 784){
      const f32x4* p0 = (const f32x4*)(xp0 + k1);
      const f32x4* p1 = (const f32x4*)(xp0 + 16*784 + k1);
      fn[0] = p0[0]; fn[1] = p0[1]; fn[2] = p1[0]; fn[3] = p1[1];
    }
    u32x4 pk0 = { f2bf_pk(f[0][0], f[0][1]), f2bf_pk(f[0][2], f[0][3]),
                  f2bf_pk(f[1][0], f[1][1]), f2bf_pk(f[1][2], f[1][3]) };
    u32x4 pk1 = { f2bf_pk(f[2][0], f[2][1]), f2bf_pk(f[2][2], f[2][3]),
                  f2bf_pk(f[3][0], f[3][1]), f2bf_pk(f[3][2], f[3][3]) };
    bf16x8 afr0 = __builtin_bit_cast(bf16x8, pk0);
    bf16x8 afr1 = __builtin_bit_cast(bf16x8, pk1);
    bf16x8 bfr0 = *(const bf16x8*)(wb0 + k0);
    bf16x8 bfr1 = *(const bf16x8*)(wb0 + 16*800 + k0);
    acc[0][0] = __builtin_amdgcn_mfma_f32_16x16x32_bf16(afr0, bfr0, acc[0][0], 0, 0, 0);
    acc[0][1] = __builtin_amdgcn_mfma_f32_16x16x32_bf16(afr0, bfr1, acc[0][1], 0, 0, 0);
    acc[1][0] = __builtin_amdgcn_mfma_f32_16x16x32_bf16(afr1, bfr0, acc[1][0], 0, 0, 0);
    acc[1][1] = __builtin_amdgcn_mfma_f32_16x16x32_bf16(afr1, bfr1, acc[1][1], 0, 0, 0);
    f[0] = fn[0]; f[1] = fn[1]; f[2] = fn[2]; f[3] = fn[3];
  }

  // epilogue: acc -> vlds (with bias)
  #pragma unroll
  for (int fi = 0; fi < 2; ++fi){
    #pragma unroll
    for (int fj = 0; fj < 2; ++fj){
      const int col = wc*32 + fj*16 + lr;
      const int r0  = wr*32 + fi*16 + lkg*4;
      const float bc = bcomb[col];
      #pragma unroll
      for (int j = 0; j < 4; ++j)
        vlds[r0 + j][col] = acc[fi][fj][j] + bc;
    }
  }
  __syncthreads();

  const int row = tid >> 2, p4 = tid & 3;

  // R1: v_tan0 = radial(v)  (in place)
  {
    f32x4 rv[4];
    float* vptr = &vlds[row][p4*16];
    #pragma unroll
    for (int i = 0; i < 4; ++i) rv[i] = ((const f32x4*)vptr)[i];
    float ssq = 0.f;
    #pragma unroll
    for (int i = 0; i < 4; ++i)
      ssq += rv[i][0]*rv[i][0] + rv[i][1]*rv[i][1] + rv[i][2]*rv[i][2] + rv[i][3]*rv[i][3];
    ssq += __shfl_xor(ssq, 1); ssq += __shfl_xor(ssq, 2);
    const float fac = radial_factor(ssq, 1.0f, 1.0f);
    #pragma unroll
    for (int i = 0; i < 4; ++i){ rv[i] *= fac; ((f32x4*)vptr)[i] = rv[i]; }
  }
  __syncthreads();

  // R2: a0 = W0aE @ (2*vt0 - mb0) + b0a ; g0 = gelu(a0)   (8 outputs/thread)
  {
    const int og = p4;
    float a0o[8];
    #pragma unroll
    for (int j = 0; j < 8; ++j) a0o[j] = cb0a[og*8 + j];
    #pragma unroll 4
    for (int k = 0; k < 64; k += 4){
      f32x4 vtv = *(const f32x4*)&vlds[row][k];
      f32x4 mm = *(const f32x4*)&cmb0[k];
      #pragma unroll
      for (int u = 0; u < 4; ++u){
        const float vc = 2.f*vtv[u] - mm[u];
        const f32x4* wp = (const f32x4*)&cW0aT[k+u][og*8];
        f32x4 w0 = wp[0], w1 = wp[1];
        #pragma unroll
        for (int j = 0; j < 4; ++j){ a0o[j] += w0[j]*vc; a0o[4+j] += w1[j]*vc; }
      }
    }
    #pragma unroll
    for (int j = 0; j < 8; ++j) gv[row][og*8 + j] = gelu_f(a0o[j]);
  }
  __syncthreads();

  // R3: v1 = W0b@g0 + b0b (1 comp/thread); v_tan1, v_comb1
  {
    const int o1 = p4;
    float a1 = cb0b[o1];
    #pragma unroll
    for (int k = 0; k < 32; k += 4){
      f32x4 gg = *(const f32x4*)&gv[row][k];
      f32x4 ww = *(const f32x4*)&cW0b[o1][k];
      a1 += gg[0]*ww[0] + gg[1]*ww[1] + gg[2]*ww[2] + gg[3]*ww[3];
    }
    float ss1 = a1*a1;
    ss1 += __shfl_xor(ss1, 1); ss1 += __shfl_xor(ss1, 2);
    const float f1v = radial_factor(ss1, 0.8f, 0.8f);
    const float vt1 = a1*f1v;
    vlds[row][64 + o1] = vt1;
    vlds[row][68 + o1] = 2.f*vt1 - cmb1[o1];
  }
  __syncthreads();

  // R4: a1 = W1aE @ vc1 + b1a ; g1 = gelu  (4 outputs/thread)
  {
    const f32x4 vc1 = *(const f32x4*)&vlds[row][68];
    #pragma unroll
    for (int j = 0; j < 4; ++j){
      const int o = p4*4 + j;
      float s1 = cb1a[o] + cW1aE[o][0]*vc1[0] + cW1aE[o][1]*vc1[1]
                         + cW1aE[o][2]*vc1[2] + cW1aE[o][3]*vc1[3];
      g1[row][o] = gelu_f(s1);
    }
  }
  __syncthreads();

  // R5: v2 = W1b@g1 + b1b (8/thread); v_tan2 -> gv
  {
    float v2[8]; float ss2 = 0.f;
    #pragma unroll
    for (int j = 0; j < 8; ++j){
      const int o = p4*8 + j;
      float s = cb1b[o];
      #pragma unroll
      for (int k = 0; k < 16; k += 4){
        f32x4 gg = *(const f32x4*)&g1[row][k];
        f32x4 ww = *(const f32x4*)&cW1b[o][k];
        s += gg[0]*ww[0] + gg[1]*ww[1] + gg[2]*ww[2] + gg[3]*ww[3];
      }
      v2[j] = s; ss2 += s*s;
    }
    ss2 += __shfl_xor(ss2, 1); ss2 += __shfl_xor(ss2, 2);
    const float f2v = radial_factor(ss2, 1.2f, 0.6f);
    #pragma unroll
    for (int j = 0; j < 8; ++j) gv[row][p4*8 + j] = v2[j]*f2v;
  }
  __syncthreads();

  // R6: out = W_out @ concat(vt0, vt1, vt2) + b_out
  for (int idx = tid; idx < 640; idx += 256){
    const int r6 = idx/10, o = idx - r6*10;
    float s = cbout[o];
    const float* wrow = &cWout[o][0];
    const float* vrow = &vlds[r6][0];
    #pragma unroll 4
    for (int k = 0; k < 68; k += 4){
      f32x4 a = *(const f32x4*)(vrow + k);
      f32x4 b = *(const f32x4*)(wrow + k);
      s += a[0]*b[0] + a[1]*b[1] + a[2]*b[2] + a[3]*b[3];
    }
    const float* v2row = &gv[r6][0];
    #pragma unroll 4
    for (int k = 0; k < 32; k += 4){
      f32x4 a = *(const f32x4*)(v2row + k);
      f32x4 b = *(const f32x4*)(wrow + 68 + k);
      s += a[0]*b[0] + a[1]*b[1] + a[2]*b[2] + a[3]*b[3];
    }
    out[(rowBase + (size_t)r6)*10 + o] = s;
  }
}

extern "C" void kernel_launch(void* const* d_in, const int* in_sizes, int n_in,
                              void* d_out, int out_size, void* d_ws, size_t ws_size,
                              hipStream_t stream)
{
  (void)n_in; (void)out_size; (void)ws_size;
  const float* x      = (const float*)d_in[0];
  const float* W_in   = (const float*)d_in[1];
  const float* b_in   = (const float*)d_in[2];
  const float* W_tan  = (const float*)d_in[3];
  const float* b_tan  = (const float*)d_in[4];
  const float* bp0    = (const float*)d_in[5];
  const float* bp1    = (const float*)d_in[6];
  /* bp2 = d_in[7] — dead in reference */
  const float* A_rot  = (const float*)d_in[8];
  const float* p_quat = (const float*)d_in[9];
  const float* q_quat = (const float*)d_in[10];
  const float* W0a    = (const float*)d_in[11];
  const float* b0a    = (const float*)d_in[12];
  const float* W0b    = (const float*)d_in[13];
  const float* b0b    = (const float*)d_in[14];
  const float* W1a    = (const float*)d_in[15];
  const float* b1a    = (const float*)d_in[16];
  const float* W1b    = (const float*)d_in[17];
  const float* b1b    = (const float*)d_in[18];
  const float* W_out  = (const float*)d_in[19];
  const float* b_out  = (const float*)d_in[20];

  char* ws = (char*)d_ws;
  unsigned short* Wc = (unsigned short*)(ws + WS_WC);
  float* bcomb = (float*)(ws + WS_BCOMB);
  float* W0aE  = (float*)(ws + WS_W0AE);
  float* brot0 = (float*)(ws + WS_BROT0);
  float* bown0 = (float*)(ws + WS_BOWN0);
  float* W0aT  = (float*)(ws + WS_W0AT);
  float* mb0   = (float*)(ws + WS_MB0);
  float* mb1   = (float*)(ws + WS_MB1);
  float* W1aE  = (float*)(ws + WS_W1AE);

  const int Brows = in_sizes[0] / 784;
  const int nblk  = Brows / 64;

  prep_a<<<60, 256, 0, stream>>>(W_in, b_in, W_tan, b_tan, A_rot, W0a, bp0,
                                 Wc, bcomb, W0aE, brot0, bown0);
  prep_small<<<1, 256, 0, stream>>>(bp1, p_quat, q_quat, b0a, W0b, b0b, W1a,
                                    W0aE, brot0, bown0, W0aT, mb0, mb1, W1aE);
  main_fused<<<nblk, 256, 0, stream>>>(x, Wc, bcomb, W0aT, mb0, mb1, W1aE,
                                       b0a, W0b, b0b, b1a, W1b, b1b,
                                       W_out, b_out, (float*)d_out);
}

// Round 5
// 84.838 us; speedup vs baseline: 2.5046x; 1.0843x over previous
//
#include <hip/hip_runtime.h>
#include <hip/hip_bf16.h>

typedef __attribute__((ext_vector_type(4))) float f32x4;
typedef __attribute__((ext_vector_type(2))) unsigned int u32x2;
typedef __attribute__((ext_vector_type(4))) unsigned int u32x4;
typedef __attribute__((ext_vector_type(8))) short bf16x8;

#define EPSF 1e-7f

// radial factor of logmap0(projx(expmap0(v*s, c), c), c)/s  applied to v, given sumsq(v)
__device__ __forceinline__ float radial_factor(float sumsq, float c, float s){
  float sc = sqrtf(c);
  float nv = sqrtf(sumsq);
  float nu = fmaxf(s*nv, EPSF);            // norm used in expmap0 (of v*s)
  float th = tanhf(sc*nu);
  float r1 = th/sc;                        // radius after expmap0
  float maxn = (1.0f - 1e-5f)/sc;
  float r2 = fminf(r1, maxn);              // radius after projx
  float n1 = fmaxf(r2, EPSF);              // norm recomputed in logmap0
  float a  = fminf(sc*n1, 1.0f - 1e-7f);
  float r3 = 0.5f*logf((1.0f + a)/(1.0f - a));   // artanh(a)
  return r3*r2/(sc*n1*nu);
}

__device__ __forceinline__ float gelu_f(float x){
  return 0.5f*x*(1.0f + erff(x*0.70710678118654752f));
}

__device__ __forceinline__ unsigned f2bf1(float f){   // RNE f32->bf16 (low 16 bits)
  unsigned u = __float_as_uint(f);
  return (u + 0x7FFFu + ((u>>16)&1u)) >> 16;
}
__device__ __forceinline__ unsigned f2bf_pk(float lo, float hi){
  unsigned ul = f2bf1(lo);
  unsigned uh = __float_as_uint(hi);
  uh = (uh + 0x7FFFu + ((uh>>16)&1u)) & 0xFFFF0000u;
  return ul | uh;
}

// ---------------- workspace layout (bytes) ----------------
#define WS_WC     0          // bf16 [64][800]
#define WS_BCOMB  204800     // f32 [64]
#define WS_W0AE   205056     // f32 [32][64]
#define WS_BROT0  213248     // f32 [5][64]
#define WS_BOWN0  214528     // f32 [5][64]
#define WS_W0AT   215808     // f32 [64][32]
#define WS_MB0    224000     // f32 [64]
#define WS_MB1    224256     // f32 [4]
#define WS_W1AE   224272     // f32 [16][4]

// ============ prep A: W_comb (blocks 0..49) + exp row-actions (blocks 50..59) ============
__global__ __launch_bounds__(256) void prep_a(
    const float* __restrict__ W_in, const float* __restrict__ b_in,
    const float* __restrict__ W_tan, const float* __restrict__ b_tan,
    const float* __restrict__ A_rot, const float* __restrict__ W0a,
    const float* __restrict__ bp0,
    unsigned short* __restrict__ Wc, float* __restrict__ bcomb,
    float* __restrict__ W0aE, float* __restrict__ brot0, float* __restrict__ bown0)
{
  __shared__ __align__(16) float Al[64][68];
  __shared__ __align__(16) float ST[64][68];   // ST[j][m] = S[m][j], S = A - A^T
  const int bid = blockIdx.x, t = threadIdx.x;

  if (bid < 50){
    if (bid == 0 && t < 64){
      float s = b_tan[t];
      for (int j = 0; j < 128; ++j) s += b_in[j]*W_tan[t*128+j];
      bcomb[t] = s;
    }
    const int g4 = bid*256 + t;              // 0..12799
    const int n = g4/200, k4 = (g4 - n*200)*4;
    f32x4 s = {0.f,0.f,0.f,0.f};
    if (k4 < 784){
      for (int j = 0; j < 128; ++j){
        float wt = W_tan[n*128+j];
        f32x4 wi = *(const f32x4*)(W_in + j*784 + k4);
        s += wt*wi;
      }
    }
    u32x2 st = { f2bf_pk(s[0], s[1]), f2bf_pk(s[2], s[3]) };
    *(u32x2*)(Wc + n*800 + k4) = st;
  } else {
    for (int m = t; m < 4096; m += 256){
      int r = m >> 6, c = m & 63;
      Al[r][c] = A_rot[m];
    }
    __syncthreads();
    for (int m = t; m < 4096; m += 256){
      int r = m >> 6, c = m & 63;
      ST[r][c] = Al[c][r] - Al[r][c];
    }
    __syncthreads();
    const int wv = t >> 6, lane = t & 63;
    const int row = (bid - 50)*4 + wv;      // 0..39, active < 37
    if (row < 37){
      float v, sgn;
      if (row < 32){ v = W0a[row*64 + lane]; sgn = 1.f; }
      else {
        const int r = row - 32;
        float b = bp0[r*64 + lane];
        float ssq = b*b;
        #pragma unroll
        for (int d = 1; d < 64; d <<= 1) ssq += __shfl_xor(ssq, d);
        float fc = radial_factor(ssq, 1.0f, 1.0f);
        v = b*fc;
        bown0[r*64 + lane] = v;
        sgn = -1.f;
      }
      float acc = v;
      for (int k = 1; k <= 12; ++k){
        const float coef = sgn/(float)k;
        float nv = 0.f;
        #pragma unroll
        for (int m = 0; m < 64; m += 4){
          f32x4 s4 = *(const f32x4*)&ST[lane][m];
          nv += __int_as_float(__builtin_amdgcn_readlane(__float_as_int(v), m+0))*s4[0];
          nv += __int_as_float(__builtin_amdgcn_readlane(__float_as_int(v), m+1))*s4[1];
          nv += __int_as_float(__builtin_amdgcn_readlane(__float_as_int(v), m+2))*s4[2];
          nv += __int_as_float(__builtin_amdgcn_readlane(__float_as_int(v), m+3))*s4[3];
        }
        nv *= coef;
        v = nv; acc += nv;
      }
      if (row < 32) W0aE[row*64 + lane] = acc;
      else          brot0[(row-32)*64 + lane] = acc;
    }
  }
}

// ============ prep B: small folds (1 block x 256) ============
__global__ __launch_bounds__(256) void prep_small(
    const float* __restrict__ bp1,
    const float* __restrict__ p_quat, const float* __restrict__ q_quat,
    const float* __restrict__ b0a, const float* __restrict__ W0b, const float* __restrict__ b0b,
    const float* __restrict__ W1a,
    const float* __restrict__ W0aE, const float* __restrict__ brot0, const float* __restrict__ bown0,
    float* __restrict__ W0aT, float* __restrict__ mb0, float* __restrict__ mb1,
    float* __restrict__ W1aE)
{
  __shared__ float g[5][32];
  __shared__ float c1[5][4];
  __shared__ float fac1[3];
  __shared__ float Mq[4][4];
  const int t = threadIdx.x;

  for (int i = t; i < 2048; i += 256){
    int o = i >> 6, k = i & 63;
    W0aT[k*32 + o] = W0aE[i];
  }
  if (t < 64){
    float s = 0.f;
    for (int r = 0; r < 5; ++r) s += bown0[r*64 + t];
    mb0[t] = s * 0.2f;
  }
  if (t < 160){
    int r = t >> 5, o = t & 31;
    float s = b0a[o];
    for (int k = 0; k < 64; ++k) s += brot0[r*64+k]*W0aE[o*64+k];
    g[r][o] = gelu_f(s);
  }
  if (t >= 192 && t < 195){
    int r = t - 192;
    float ssq = 0.f;
    for (int j = 0; j < 4; ++j){ float b = bp1[r*4+j]; ssq += b*b; }
    fac1[r] = radial_factor(ssq, 0.8f, 1.0f);
  }
  if (t == 224){
    float pw=p_quat[0],px=p_quat[1],py=p_quat[2],pz=p_quat[3];
    float n1 = sqrtf(pw*pw+px*px+py*py+pz*pz) + EPSF;
    pw/=n1; px/=n1; py/=n1; pz/=n1;
    float qw=q_quat[0],qx=q_quat[1],qy=q_quat[2],qz=q_quat[3];
    float n2 = sqrtf(qw*qw+qx*qx+qy*qy+qz*qz) + EPSF;
    qw/=n2; qx/=n2; qy/=n2; qz/=n2;
    float Lp[4][4] = {{pw,-px,-py,-pz},{px,pw,-pz,py},{py,pz,pw,-px},{pz,-py,px,pw}};
    float Rq[4][4] = {{qw,-qx,-qy,-qz},{qx,qw,qz,-qy},{qy,-qz,qw,qx},{qz,qy,-qx,qw}};
    #pragma unroll
    for (int i = 0; i < 4; ++i)
      #pragma unroll
      for (int k = 0; k < 4; ++k){
        float s = 0.f;
        #pragma unroll
        for (int m = 0; m < 4; ++m) s += Rq[i][m]*Lp[m][k];
        Mq[i][k] = s;
      }
  }
  __syncthreads();
  if (t < 20){
    int r = t >> 2, o = t & 3;
    float s = b0b[o];
    for (int k = 0; k < 32; ++k) s += g[r][k]*W0b[o*32+k];
    c1[r][o] = s;
  }
  __syncthreads();
  if (t < 4){
    float s = 0.f;
    for (int r = 0; r < 3; ++r) s += bp1[r*4+t]*fac1[r];
    for (int r = 0; r < 5; ++r) s += c1[r][t];
    mb1[t] = s * 0.125f;
  }
  if (t >= 64 && t < 128){
    int i = t - 64, o = i >> 2, kq = i & 3;
    float s = 0.f;
    #pragma unroll
    for (int j = 0; j < 4; ++j) s += W1a[o*4+j]*Mq[j][kq];
    W1aE[o*4+kq] = s;
  }
}

// ============ fused main: depth-4 pipelined MFMA GEMM -> row phase ============
__global__ __launch_bounds__(256, 3) void main_fused(
    const float* __restrict__ x,
    const unsigned short* __restrict__ Wc,
    const float* __restrict__ bcomb,
    const float* __restrict__ W0aT,
    const float* __restrict__ mb0g, const float* __restrict__ mb1g,
    const float* __restrict__ W1aEg,
    const float* __restrict__ b0a, const float* __restrict__ W0b, const float* __restrict__ b0b,
    const float* __restrict__ b1a, const float* __restrict__ W1b, const float* __restrict__ b1b,
    const float* __restrict__ Wout, const float* __restrict__ bout,
    float* __restrict__ out)
{
  __shared__ __align__(16) float vlds[64][76];   // GEMM out / vt0 [0..64), vt1 [64..68), vc1 [68..72)
  __shared__ __align__(16) float gv[64][36];     // g0 during R2/R3, vt2 during R5/R6
  __shared__ __align__(16) float g1[64][20];
  __shared__ __align__(16) float cW0aT[64][32];  // [k][o]
  __shared__ __align__(16) float cmb0[64];
  __shared__ __align__(16) float cW0b[4][32];
  __shared__ __align__(16) float cW1b[32][16];
  __shared__ __align__(16) float cWout[10][100];
  __shared__ __align__(16) float cW1aE[16][4];
  __shared__ float cb0a[32], cb0b[4], cmb1[4], cb1a[16], cb1b[32], cbout[12];

  const int tid = threadIdx.x;
  const size_t rowBase = (size_t)blockIdx.x * 64;

  // ---- stage all row-phase weights into LDS (overlaps with GEMM x loads) ----
  for (int i = tid; i < 2048; i += 256){
    const int k = i >> 5, o = i & 31;
    cW0aT[k][o] = W0aT[k*32 + o];
  }
  if (tid < 64)  cmb0[tid] = mb0g[tid];
  if (tid < 32)  cb0a[tid] = b0a[tid];
  if (tid < 128) ((float*)cW0b)[tid] = W0b[tid];
  if (tid < 4)   { cb0b[tid] = b0b[tid]; cmb1[tid] = mb1g[tid]; }
  if (tid < 64)  ((float*)cW1aE)[tid] = W1aEg[tid];
  if (tid < 16)  cb1a[tid] = b1a[tid];
  if (tid < 32)  cb1b[tid] = b1b[tid];
  if (tid < 10)  cbout[tid] = bout[tid];
  for (int i = tid; i < 512; i += 256)  ((float*)cW1b)[i] = W1b[i];
  for (int i = tid; i < 1000; i += 256) ((float*)cWout)[i] = Wout[i];

  // ---- GEMM: v[64][64] = x_tile @ Wc^T + bcomb (bf16 MFMA 16x16x32) ----
  const int lane = tid & 63;
  const int w    = tid >> 6;
  const int wr   = w >> 1, wc = w & 1;
  const int lr   = lane & 15, lkg = lane >> 4;
  const float* xp0 = x + (rowBase + (size_t)(wr*32 + lr)) * 784;
  const unsigned short* wb0 = Wc + (size_t)(wc*32 + lr) * 800;

  f32x4 acc[2][2] = {};
  f32x4 fb[4][4];                 // A prefetch ring (depth 4), static indices only
  bf16x8 bb[4][2];                // B prefetch ring
  const f32x4 fz = {0.f,0.f,0.f,0.f};

#define LOAD_AB(d, kidx) do{                                            \
    const int kq_ = (kidx)*32 + lkg*8;                                  \
    if (kq_ < 784){                                                     \
      const f32x4* pa_ = (const f32x4*)(xp0 + kq_);                     \
      const f32x4* pb_ = (const f32x4*)(xp0 + 16*784 + kq_);            \
      fb[d][0]=pa_[0]; fb[d][1]=pa_[1]; fb[d][2]=pb_[0]; fb[d][3]=pb_[1];\
    } else {                                                            \
      fb[d][0]=fz; fb[d][1]=fz; fb[d][2]=fz; fb[d][3]=fz;               \
    }                                                                   \
    if ((kidx) < 25){                                                   \
      bb[d][0] = *(const bf16x8*)(wb0 + kq_);                           \
      bb[d][1] = *(const bf16x8*)(wb0 + 16*800 + kq_);                  \
    }                                                                   \
  }while(0)

#define COMPUTE(d) do{                                                              \
    u32x4 pk0_ = { f2bf_pk(fb[d][0][0], fb[d][0][1]), f2bf_pk(fb[d][0][2], fb[d][0][3]), \
                   f2bf_pk(fb[d][1][0], fb[d][1][1]), f2bf_pk(fb[d][1][2], fb[d][1][3]) };\
    u32x4 pk1_ = { f2bf_pk(fb[d][2][0], fb[d][2][1]), f2bf_pk(fb[d][2][2], fb[d][2][3]), \
                   f2bf_pk(fb[d][3][0], fb[d][3][1]), f2bf_pk(fb[d][3][2], fb[d][3][3]) };\
    bf16x8 a0_ = __builtin_bit_cast(bf16x8, pk0_);                                  \
    bf16x8 a1_ = __builtin_bit_cast(bf16x8, pk1_);                                  \
    acc[0][0] = __builtin_amdgcn_mfma_f32_16x16x32_bf16(a0_, bb[d][0], acc[0][0], 0,0,0);\
    acc[0][1] = __builtin_amdgcn_mfma_f32_16x16x32_bf16(a0_, bb[d][1], acc[0][1], 0,0,0);\
    acc[1][0] = __builtin_amdgcn_mfma_f32_16x16x32_bf16(a1_, bb[d][0], acc[1][0], 0,0,0);\
    acc[1][1] = __builtin_amdgcn_mfma_f32_16x16x32_bf16(a1_, bb[d][1], acc[1][1], 0,0,0);\
  }while(0)

  LOAD_AB(0, 0); LOAD_AB(1, 1); LOAD_AB(2, 2); LOAD_AB(3, 3);
  for (int kk = 0; kk < 24; kk += 4){
    COMPUTE(0); LOAD_AB(0, kk+4);
    COMPUTE(1); LOAD_AB(1, kk+5);
    COMPUTE(2); LOAD_AB(2, kk+6);
    COMPUTE(3); LOAD_AB(3, kk+7);
  }
  COMPUTE(0);   // kk = 24 (loaded during kk=20 group)

#undef LOAD_AB
#undef COMPUTE

  // epilogue: acc -> vlds (with bias)
  #pragma unroll
  for (int fi = 0; fi < 2; ++fi){
    #pragma unroll
    for (int fj = 0; fj < 2; ++fj){
      const int col = wc*32 + fj*16 + lr;
      const int r0  = wr*32 + fi*16 + lkg*4;
      const float bc = bcomb[col];
      #pragma unroll
      for (int j = 0; j < 4; ++j)
        vlds[r0 + j][col] = acc[fi][fj][j] + bc;
    }
  }
  __syncthreads();

  const int row = tid >> 2, p4 = tid & 3;

  // R1: v_tan0 = radial(v)  (in place)
  {
    f32x4 rv[4];
    float* vptr = &vlds[row][p4*16];
    #pragma unroll
    for (int i = 0; i < 4; ++i) rv[i] = ((const f32x4*)vptr)[i];
    float ssq = 0.f;
    #pragma unroll
    for (int i = 0; i < 4; ++i)
      ssq += rv[i][0]*rv[i][0] + rv[i][1]*rv[i][1] + rv[i][2]*rv[i][2] + rv[i][3]*rv[i][3];
    ssq += __shfl_xor(ssq, 1); ssq += __shfl_xor(ssq, 2);
    const float fac = radial_factor(ssq, 1.0f, 1.0f);
    #pragma unroll
    for (int i = 0; i < 4; ++i){ rv[i] *= fac; ((f32x4*)vptr)[i] = rv[i]; }
  }
  __syncthreads();

  // R2: a0 = W0aE @ (2*vt0 - mb0) + b0a ; g0 = gelu(a0)   (8 outputs/thread)
  {
    const int og = p4;
    float a0o[8];
    #pragma unroll
    for (int j = 0; j < 8; ++j) a0o[j] = cb0a[og*8 + j];
    #pragma unroll 4
    for (int k = 0; k < 64; k += 4){
      f32x4 vtv = *(const f32x4*)&vlds[row][k];
      f32x4 mm = *(const f32x4*)&cmb0[k];
      #pragma unroll
      for (int u = 0; u < 4; ++u){
        const float vc = 2.f*vtv[u] - mm[u];
        const f32x4* wp = (const f32x4*)&cW0aT[k+u][og*8];
        f32x4 w0 = wp[0], w1 = wp[1];
        #pragma unroll
        for (int j = 0; j < 4; ++j){ a0o[j] += w0[j]*vc; a0o[4+j] += w1[j]*vc; }
      }
    }
    #pragma unroll
    for (int j = 0; j < 8; ++j) gv[row][og*8 + j] = gelu_f(a0o[j]);
  }
  __syncthreads();

  // R3: v1 = W0b@g0 + b0b (1 comp/thread); v_tan1, v_comb1
  {
    const int o1 = p4;
    float a1 = cb0b[o1];
    #pragma unroll
    for (int k = 0; k < 32; k += 4){
      f32x4 gg = *(const f32x4*)&gv[row][k];
      f32x4 ww = *(const f32x4*)&cW0b[o1][k];
      a1 += gg[0]*ww[0] + gg[1]*ww[1] + gg[2]*ww[2] + gg[3]*ww[3];
    }
    float ss1 = a1*a1;
    ss1 += __shfl_xor(ss1, 1); ss1 += __shfl_xor(ss1, 2);
    const float f1v = radial_factor(ss1, 0.8f, 0.8f);
    const float vt1 = a1*f1v;
    vlds[row][64 + o1] = vt1;
    vlds[row][68 + o1] = 2.f*vt1 - cmb1[o1];
  }
  __syncthreads();

  // R4: a1 = W1aE @ vc1 + b1a ; g1 = gelu  (4 outputs/thread)
  {
    const f32x4 vc1 = *(const f32x4*)&vlds[row][68];
    #pragma unroll
    for (int j = 0; j < 4; ++j){
      const int o = p4*4 + j;
      float s1 = cb1a[o] + cW1aE[o][0]*vc1[0] + cW1aE[o][1]*vc1[1]
                         + cW1aE[o][2]*vc1[2] + cW1aE[o][3]*vc1[3];
      g1[row][o] = gelu_f(s1);
    }
  }
  __syncthreads();

  // R5: v2 = W1b@g1 + b1b (8/thread); v_tan2 -> gv
  {
    float v2[8]; float ss2 = 0.f;
    #pragma unroll
    for (int j = 0; j < 8; ++j){
      const int o = p4*8 + j;
      float s = cb1b[o];
      #pragma unroll
      for (int k = 0; k < 16; k += 4){
        f32x4 gg = *(const f32x4*)&g1[row][k];
        f32x4 ww = *(const f32x4*)&cW1b[o][k];
        s += gg[0]*ww[0] + gg[1]*ww[1] + gg[2]*ww[2] + gg[3]*ww[3];
      }
      v2[j] = s; ss2 += s*s;
    }
    ss2 += __shfl_xor(ss2, 1); ss2 += __shfl_xor(ss2, 2);
    const float f2v = radial_factor(ss2, 1.2f, 0.6f);
    #pragma unroll
    for (int j = 0; j < 8; ++j) gv[row][p4*8 + j] = v2[j]*f2v;
  }
  __syncthreads();

  // R6: out = W_out @ concat(vt0, vt1, vt2) + b_out
  for (int idx = tid; idx < 640; idx += 256){
    const int r6 = idx/10, o = idx - r6*10;
    float s = cbout[o];
    const float* wrow = &cWout[o][0];
    const float* vrow = &vlds[r6][0];
    #pragma unroll 4
    for (int k = 0; k < 68; k += 4){
      f32x4 a = *(const f32x4*)(vrow + k);
      f32x4 b = *(const f32x4*)(wrow + k);
      s += a[0]*b[0] + a[1]*b[1] + a[2]*b[2] + a[3]*b[3];
    }
    const float* v2row = &gv[r6][0];
    #pragma unroll 4
    for (int k = 0; k < 32; k += 4){
      f32x4 a = *(const f32x4*)(v2row + k);
      f32x4 b = *(const f32x4*)(wrow + 68 + k);
      s += a[0]*b[0] + a[1]*b[1] + a[2]*b[2] + a[3]*b[3];
    }
    out[(rowBase + (size_t)r6)*10 + o] = s;
  }
}

extern "C" void kernel_launch(void* const* d_in, const int* in_sizes, int n_in,
                              void* d_out, int out_size, void* d_ws, size_t ws_size,
                              hipStream_t stream)
{
  (void)n_in; (void)out_size; (void)ws_size;
  const float* x      = (const float*)d_in[0];
  const float* W_in   = (const float*)d_in[1];
  const float* b_in   = (const float*)d_in[2];
  const float* W_tan  = (const float*)d_in[3];
  const float* b_tan  = (const float*)d_in[4];
  const float* bp0    = (const float*)d_in[5];
  const float* bp1    = (const float*)d_in[6];
  /* bp2 = d_in[7] — dead in reference */
  const float* A_rot  = (const float*)d_in[8];
  const float* p_quat = (const float*)d_in[9];
  const float* q_quat = (const float*)d_in[10];
  const float* W0a    = (const float*)d_in[11];
  const float* b0a    = (const float*)d_in[12];
  const float* W0b    = (const float*)d_in[13];
  const float* b0b    = (const float*)d_in[14];
  const float* W1a    = (const float*)d_in[15];
  const float* b1a    = (const float*)d_in[16];
  const float* W1b    = (const float*)d_in[17];
  const float* b1b    = (const float*)d_in[18];
  const float* W_out  = (const float*)d_in[19];
  const float* b_out  = (const float*)d_in[20];

  char* ws = (char*)d_ws;
  unsigned short* Wc = (unsigned short*)(ws + WS_WC);
  float* bcomb = (float*)(ws + WS_BCOMB);
  float* W0aE  = (float*)(ws + WS_W0AE);
  float* brot0 = (float*)(ws + WS_BROT0);
  float* bown0 = (float*)(ws + WS_BOWN0);
  float* W0aT  = (float*)(ws + WS_W0AT);
  float* mb0   = (float*)(ws + WS_MB0);
  float* mb1   = (float*)(ws + WS_MB1);
  float* W1aE  = (float*)(ws + WS_W1AE);

  const int Brows = in_sizes[0] / 784;
  const int nblk  = Brows / 64;

  prep_a<<<60, 256, 0, stream>>>(W_in, b_in, W_tan, b_tan, A_rot, W0a, bp0,
                                 Wc, bcomb, W0aE, brot0, bown0);
  prep_small<<<1, 256, 0, stream>>>(bp1, p_quat, q_quat, b0a, W0b, b0b, W1a,
                                    W0aE, brot0, bown0, W0aT, mb0, mb1, W1aE);
  main_fused<<<nblk, 256, 0, stream>>>(x, Wc, bcomb, W0aT, mb0, mb1, W1aE,
                                       b0a, W0b, b0b, b1a, W1b, b1b,
                                       W_out, b_out, (float*)d_out);
}